// Round 1
// baseline (3519.875 us; speedup 1.0000x reference)
//
#include <hip/hip_runtime.h>
#include <hip/hip_bf16.h>

// ---------------------------------------------------------------------------
// SComGNN: item GEMM -> spmm x2 -> low/mid GEMM -> BN stats -> gather-norm ->
// stacked qkv GEMM -> attn -> stacked qkv GEMM -> attn -> Wcat GEMM -> loss
// ---------------------------------------------------------------------------

typedef __attribute__((ext_vector_type(4))) float  f32x4;
typedef __attribute__((ext_vector_type(2))) float  f32x2;
typedef __attribute__((ext_vector_type(8))) short  s16x8;
typedef __attribute__((ext_vector_type(4))) short  s16x4;
typedef __attribute__((ext_vector_type(8))) __bf16 bf16x8;

#define NN   50000
#define EE   1600000
#define BQ   4096
#define NNEG 4

__device__ __forceinline__ short f2b(float x) {
    union { float f; unsigned u; } c; c.f = x;
    unsigned r = c.u + 0x7FFF + ((c.u >> 16) & 1);   // RNE to bf16
    return (short)(r >> 16);
}

// ---------------------------------------------------------------------------
// Generic 128-col-tile bf16 MFMA GEMM: Y[rows x ldY cols] = act(A @ W + bias)
// A fp32 row-major (stride K); WT bf16 row-major [ncols][K] (transposed W).
// grid.x = row tiles, grid.y = col tiles (c0 = 128*blockIdx.y).
// TWOSRC: A = alpha*A1 + beta*A2 (staged). PRICE: += ptab[price[row]*128+col].
// ---------------------------------------------------------------------------
template<bool TWOSRC, bool PRICE, bool RELU>
__global__ __launch_bounds__(256)
void gemm_bf16(const float* __restrict__ A1, const float* __restrict__ A2,
               float alpha, float beta,
               const short* __restrict__ WT, const float* __restrict__ bias,
               const int* __restrict__ price, const float* __restrict__ ptab,
               float* __restrict__ Y, int ldY, int rows, int K)
{
    __shared__ short Alds[128][32];
    __shared__ short Wlds[128][32];

    const int t    = threadIdx.x;
    const int lane = t & 63;
    const int w    = t >> 6;
    const int r0   = blockIdx.x * 128;
    const int c0   = blockIdx.y * 128;
    const short* WTb = WT + (size_t)c0 * K;

    f32x4 acc[4][4];
#pragma unroll
    for (int m = 0; m < 4; ++m)
#pragma unroll
        for (int n = 0; n < 4; ++n) acc[m][n] = (f32x4)0.f;

    const int srow = t >> 3;          // A stage: 0..31 (x4 iters)
    const int skk  = (t & 7) * 4;
    const int wn   = t >> 1;          // W stage: 0..127
    const int wkp  = (t & 1) * 16;

    const int wr   = (w >> 1) * 64;
    const int wc   = (w & 1) * 64;
    const int rsel = lane & 15;
    const int kb   = (lane >> 4) * 8;

    for (int k0 = 0; k0 < K; k0 += 32) {
        // ---- stage A tile (128 x 32) with fp32->bf16 convert, XOR swizzle
#pragma unroll
        for (int i = 0; i < 4; ++i) {
            int r  = srow + i * 32;
            int rg = r0 + r; rg = rg < rows ? rg : rows - 1;
            float4 va = *(const float4*)(A1 + (size_t)rg * K + (k0 + skk));
            if (TWOSRC) {
                float4 vb = *(const float4*)(A2 + (size_t)rg * K + (k0 + skk));
                va.x = alpha * va.x + beta * vb.x;
                va.y = alpha * va.y + beta * vb.y;
                va.z = alpha * va.z + beta * vb.z;
                va.w = alpha * va.w + beta * vb.w;
            }
            s16x4 sv; sv[0]=f2b(va.x); sv[1]=f2b(va.y); sv[2]=f2b(va.z); sv[3]=f2b(va.w);
            int sw = ((r >> 1) & 3) * 8;
            *(s16x4*)&Alds[r][skk ^ sw] = sv;
        }
        // ---- stage W tile (128 cols x 32 k), already bf16
        {
            const short* p = WTb + (size_t)wn * K + (k0 + wkp);
            s16x8 w0 = *(const s16x8*)p;
            s16x8 w1 = *(const s16x8*)(p + 8);
            int sw = ((wn >> 1) & 3) * 8;
            *(s16x8*)&Wlds[wn][wkp ^ sw]       = w0;
            *(s16x8*)&Wlds[wn][(wkp + 8) ^ sw] = w1;
        }
        __syncthreads();

        s16x8 af[4], bfr[4];
#pragma unroll
        for (int m = 0; m < 4; ++m) {
            int r = wr + m * 16 + rsel;
            af[m] = *(const s16x8*)&Alds[r][kb ^ (((r >> 1) & 3) * 8)];
        }
#pragma unroll
        for (int n = 0; n < 4; ++n) {
            int r = wc + n * 16 + rsel;
            bfr[n] = *(const s16x8*)&Wlds[r][kb ^ (((r >> 1) & 3) * 8)];
        }
#pragma unroll
        for (int m = 0; m < 4; ++m)
#pragma unroll
            for (int n = 0; n < 4; ++n)
                acc[m][n] = __builtin_amdgcn_mfma_f32_16x16x32_bf16(
                    __builtin_bit_cast(bf16x8, af[m]),
                    __builtin_bit_cast(bf16x8, bfr[n]), acc[m][n], 0, 0, 0);
        __syncthreads();
    }

    // ---- epilogue: D layout col=lane&15, row=(lane>>4)*4+i
    const int crow = (lane >> 4) * 4;
#pragma unroll
    for (int m = 0; m < 4; ++m) {
        int rbase = r0 + wr + m * 16 + crow;
#pragma unroll
        for (int i = 0; i < 4; ++i) {
            int gr = rbase + i;
            bool ok = (gr < rows);
            int pidx = 0;
            if (PRICE) pidx = ok ? price[gr] : 0;
#pragma unroll
            for (int n = 0; n < 4; ++n) {
                int coll = wc + n * 16 + rsel;
                int cc   = c0 + coll;
                float v  = acc[m][n][i];
                if (bias)  v += bias[cc];
                if (PRICE) v += ptab[pidx * 128 + coll];
                if (RELU)  v = fmaxf(v, 0.f);
                if (ok) Y[(size_t)gr * ldY + cc] = v;
            }
        }
    }
}

// ---------------------------------------------------------------------------
// SpMM: y[row[e]] += val[e] * x[col[e]]  (one wave per edge-iteration, D=128)
// ---------------------------------------------------------------------------
__global__ __launch_bounds__(256)
void spmm_kernel(const int* __restrict__ row, const int* __restrict__ col,
                 const float* __restrict__ val, const float* __restrict__ x,
                 float* __restrict__ y, int E)
{
    int gw   = (blockIdx.x * 256 + threadIdx.x) >> 6;
    int lane = threadIdx.x & 63;
    int nw   = (gridDim.x * 256) >> 6;
    int d    = lane * 2;
    for (int base = gw * 64; base < E; base += nw * 64) {
        int e = base + lane;
        int r = 0, c = 0; float v = 0.f;
        if (e < E) { r = row[e]; c = col[e]; v = val[e]; }
        int cnt = min(64, E - base);
        for (int j = 0; j < cnt; ++j) {
            int   rj = __shfl(r, j);
            int   cj = __shfl(c, j);
            float vj = __shfl(v, j);
            f32x2 xv = *(const f32x2*)(x + (size_t)cj * 128 + d);
            atomicAdd(&y[(size_t)rj * 128 + d],     vj * xv.x);
            atomicAdd(&y[(size_t)rj * 128 + d + 1], vj * xv.y);
        }
    }
}

// ---------------------------------------------------------------------------
// Column stats (sum, sumsq) for BN over low (blockIdx.y=0) / mid (=1)
// ---------------------------------------------------------------------------
__global__ __launch_bounds__(256)
void colstats(const float* __restrict__ low, const float* __restrict__ mid,
              float* __restrict__ stats, int nrows)
{
    const float* src = blockIdx.y ? mid : low;
    int c = threadIdx.x & 127;
    int h = threadIdx.x >> 7;
    int rs = blockIdx.x * 512;
    int re = min(rs + 512, nrows);
    float s1 = 0.f, s2 = 0.f;
    for (int r = rs + h; r < re; r += 2) {
        float xv = src[(size_t)r * 128 + c];
        s1 += xv; s2 += xv * xv;
    }
    __shared__ float l1[256], l2[256];
    l1[threadIdx.x] = s1; l2[threadIdx.x] = s2;
    __syncthreads();
    if (h == 0) {
        s1 = l1[c] + l1[128 + c];
        s2 = l2[c] + l2[128 + c];
        atomicAdd(&stats[blockIdx.y * 256 + c],       s1);
        atomicAdd(&stats[blockIdx.y * 256 + 128 + c], s2);
    }
}

__global__ __launch_bounds__(256)
void bn_scalebias(const float* __restrict__ stats,
                  const float* g1, const float* b1,
                  const float* g2, const float* b2,
                  float* __restrict__ sb, float inv_n)
{
    int t = threadIdx.x;
    int mat = t >> 7, c = t & 127;
    float mean = stats[mat * 256 + c] * inv_n;
    float var  = stats[mat * 256 + 128 + c] * inv_n - mean * mean;
    float s = (mat ? g2[c] : g1[c]) * rsqrtf(var + 1e-5f);
    float tt = (mat ? b2[c] : b1[c]) - mean * s;
    sb[mat * 256 + c] = s;
    sb[mat * 256 + 128 + c] = tt;
}

// out rows: r in [0, nb*nslots): node = ts[b*6+slot0+j]; writes 2x128 per r
__global__ __launch_bounds__(256)
void gather_norm(const float* __restrict__ low, const float* __restrict__ mid,
                 const float* __restrict__ sb, const int* __restrict__ ts,
                 float* __restrict__ out, int nb, int slot0, int nslots)
{
    int idx = blockIdx.x * 256 + threadIdx.x;
    if (idx >= nb * nslots * 256) return;
    int c   = idx & 127;
    int seq = (idx >> 7) & 1;
    int r   = idx >> 8;
    int b = r / nslots, j = r - b * nslots;
    int node = ts[b * 6 + slot0 + j];
    const float* src = seq ? mid : low;
    float xv = src[(size_t)node * 128 + c];
    out[(size_t)r * 256 + seq * 128 + c] = xv * sb[seq * 256 + c] + sb[seq * 256 + 128 + c];
}

// ---------------------------------------------------------------------------
// 2-token attention, softmax over axis=1 (queries). qkv rows stride 384:
// q at +0, k at +128, v at +256. One wave per batch element.
// ---------------------------------------------------------------------------
__global__ __launch_bounds__(256)
void attn_kernel(const float* __restrict__ qbase, const float* __restrict__ kvbase,
                 float* __restrict__ h, int nb, int qshift, int kvshift)
{
    int gw   = (blockIdx.x * 256 + threadIdx.x) >> 6;
    int lane = threadIdx.x & 63;
    if (gw >= nb) return;
    int qb = (gw >> qshift) * 2;
    int kb = (gw >> kvshift) * 2;
    const float* q0 = qbase + (size_t)qb * 384;
    const float* q1 = q0 + 384;
    const float* k0 = kvbase + (size_t)kb * 384 + 128;
    const float* k1 = k0 + 384;
    const float* v0 = kvbase + (size_t)kb * 384 + 256;
    const float* v1 = v0 + 384;
    int d = lane * 2;
    f32x2 q0v = *(const f32x2*)(q0 + d);
    f32x2 q1v = *(const f32x2*)(q1 + d);
    f32x2 k0v = *(const f32x2*)(k0 + d);
    f32x2 k1v = *(const f32x2*)(k1 + d);
    float s00 = q0v.x*k0v.x + q0v.y*k0v.y;
    float s01 = q0v.x*k1v.x + q0v.y*k1v.y;
    float s10 = q1v.x*k0v.x + q1v.y*k0v.y;
    float s11 = q1v.x*k1v.x + q1v.y*k1v.y;
#pragma unroll
    for (int off = 32; off; off >>= 1) {
        s00 += __shfl_xor(s00, off);
        s01 += __shfl_xor(s01, off);
        s10 += __shfl_xor(s10, off);
        s11 += __shfl_xor(s11, off);
    }
    const float scale = 0.08838834764831845f;   // 1/sqrt(128)
    s00 *= scale; s01 *= scale; s10 *= scale; s11 *= scale;
    // softmax over the QUERY axis (per key column)
    float m0 = fmaxf(s00, s10), m1 = fmaxf(s01, s11);
    float e00 = __expf(s00 - m0), e10 = __expf(s10 - m0);
    float e01 = __expf(s01 - m1), e11 = __expf(s11 - m1);
    float i0 = 1.f / (e00 + e10), i1 = 1.f / (e01 + e11);
    float a00 = e00 * i0, a10 = e10 * i0;
    float a01 = e01 * i1, a11 = e11 * i1;
    f32x2 v0v = *(const f32x2*)(v0 + d);
    f32x2 v1v = *(const f32x2*)(v1 + d);
    f32x2 h0, h1;
    h0.x = a00*v0v.x + a01*v1v.x;  h0.y = a00*v0v.y + a01*v1v.y;
    h1.x = a10*v0v.x + a11*v1v.x;  h1.y = a10*v0v.y + a11*v1v.y;
    *(f32x2*)(h + (size_t)(gw * 2)     * 128 + d) = h0;
    *(f32x2*)(h + (size_t)(gw * 2 + 1) * 128 + d) = h1;
}

// ---------------------------------------------------------------------------
// scores: [0,4096)=dot(cat[b],cat[4096+b]) ; [4096,20480)=dot(cat[8192+n],cat[24576+n])
// ---------------------------------------------------------------------------
__global__ __launch_bounds__(256)
void scores_kernel(const float* __restrict__ cat, float* __restrict__ scores)
{
    int gw   = (blockIdx.x * 256 + threadIdx.x) >> 6;
    int lane = threadIdx.x & 63;
    if (gw >= 20480) return;
    const float *pa, *pb;
    if (gw < BQ) { pa = cat + (size_t)gw * 128;            pb = cat + (size_t)(BQ + gw) * 128; }
    else { int n = gw - BQ; pa = cat + (size_t)(2*BQ + n) * 128; pb = cat + (size_t)(2*BQ + BQ*NNEG + n) * 128; }
    f32x2 a = *(const f32x2*)(pa + lane * 2);
    f32x2 b = *(const f32x2*)(pb + lane * 2);
    float s = a.x * b.x + a.y * b.y;
#pragma unroll
    for (int off = 32; off; off >>= 1) s += __shfl_xor(s, off);
    if (lane == 0) scores[gw] = s;
}

__global__ __launch_bounds__(256)
void loss_kernel(const float* __restrict__ scores, float* __restrict__ out)
{
    int t = threadIdx.x;
    float acc = 0.f;
    for (int i = t; i < BQ * NNEG; i += 256) {
        int b = i >> 2;
        float x = scores[b] - scores[BQ + i];
        float sig = 1.f / (1.f + __expf(-x));
        acc += __logf(sig + 1e-9f);
    }
    __shared__ float red[256];
    red[t] = acc; __syncthreads();
    for (int s = 128; s > 0; s >>= 1) { if (t < s) red[t] += red[t + s]; __syncthreads(); }
    if (t == 0) out[0] = -red[0] / (float)(BQ * NNEG);
}

// ---------------------------------------------------------------------------
// Weight-pack kernels (run every call; tiny)
// ---------------------------------------------------------------------------
// WcT[n][k] (bf16, [128][1536]) : k<768 -> (W2@We_a)^T, else (W3@We_b)^T
__global__ void pack_wc(const float* __restrict__ W2, const float* __restrict__ W3,
                        const float* __restrict__ We, short* __restrict__ WcT)
{
    int k = blockIdx.x, n = threadIdx.x;
    const float* Wrow = (k < 768) ? (W2 + (size_t)k * 128) : (W3 + (size_t)(k - 768) * 128);
    const float* Web  = We + ((k < 768) ? 0 : 128 * 128);
    float acc = 0.f;
    for (int j = 0; j < 128; ++j) acc += Wrow[j] * Web[j * 128 + n];
    WcT[(size_t)n * 1536 + k] = f2b(acc);
}

__global__ void pack_ptab(const float* __restrict__ PT, const float* __restrict__ We,
                          float* __restrict__ ptab2)
{
    int p = blockIdx.x, n = threadIdx.x;
    const float* Web = We + 256 * 128;
    float acc = 0.f;
    for (int j = 0; j < 128; ++j) acc += PT[p * 128 + j] * Web[j * 128 + n];
    ptab2[p * 128 + n] = acc;
}

__global__ void pack_biasc(const float* b2, const float* b3, const float* bemb,
                           const float* __restrict__ We, float* __restrict__ bias_c)
{
    int n = threadIdx.x;
    float acc = bemb[n];
    for (int j = 0; j < 128; ++j)
        acc += b2[j] * We[j * 128 + n] + b3[j] * We[(128 + j) * 128 + n];
    bias_c[n] = acc;
}

// WT[n][k] = W[k][n] (bf16); grid.x = K, 128 threads
__global__ void pack_wt(const float* __restrict__ W, short* __restrict__ WT, int K)
{
    int k = blockIdx.x, n = threadIdx.x;
    WT[(size_t)n * K + k] = f2b(W[(size_t)k * 128 + n]);
}

// concat q|k|v transposed: WT[384][128], bias[384]; grid.x = 128 (k), 384 threads
__global__ void pack_wt3(const float* Wq, const float* Wk, const float* Wv,
                         const float* bq, const float* bk, const float* bv,
                         short* __restrict__ WT, float* __restrict__ bout)
{
    int k = blockIdx.x, n = threadIdx.x;
    const float* W = (n < 128) ? Wq : ((n < 256) ? Wk : Wv);
    int nl = n & 127;
    WT[(size_t)n * 128 + k] = f2b(W[k * 128 + nl]);
    if (k == 0) {
        const float* b = (n < 128) ? bq : ((n < 256) ? bk : bv);
        bout[n] = b[nl];
    }
}

// ---------------------------------------------------------------------------
extern "C" void kernel_launch(void* const* d_in, const int* in_sizes, int n_in,
                              void* d_out, int out_size, void* d_ws, size_t ws_size,
                              hipStream_t stream)
{
    const float* features = (const float*)d_in[0];
    const int*   price    = (const int*)  d_in[1];
    const int*   adj_row  = (const int*)  d_in[2];
    const int*   adj_col  = (const int*)  d_in[3];
    const float* adj_val  = (const float*)d_in[4];
    const int*   train_set= (const int*)  d_in[5];
    const float* W_cid2   = (const float*)d_in[6];
    const float* b_cid2   = (const float*)d_in[7];
    const float* W_cid3   = (const float*)d_in[8];
    const float* b_cid3   = (const float*)d_in[9];
    const float* ptable   = (const float*)d_in[10];
    const float* W_emb    = (const float*)d_in[11];
    const float* b_emb    = (const float*)d_in[12];
    const float* W_low    = (const float*)d_in[13];
    const float* W_mid    = (const float*)d_in[14];
    const float* bn1_g    = (const float*)d_in[15];
    const float* bn1_b    = (const float*)d_in[16];
    const float* bn2_g    = (const float*)d_in[17];
    const float* bn2_b    = (const float*)d_in[18];
    const float* Wq1 = (const float*)d_in[19]; const float* bq1 = (const float*)d_in[20];
    const float* Wk1 = (const float*)d_in[21]; const float* bk1 = (const float*)d_in[22];
    const float* Wv1 = (const float*)d_in[23]; const float* bv1 = (const float*)d_in[24];
    const float* Wq2 = (const float*)d_in[25]; const float* bq2 = (const float*)d_in[26];
    const float* Wk2 = (const float*)d_in[27]; const float* bk2 = (const float*)d_in[28];
    const float* Wv2 = (const float*)d_in[29]; const float* bv2 = (const float*)d_in[30];
    const float* Wcat= (const float*)d_in[31]; const float* bcat= (const float*)d_in[32];

    float* ws = (float*)d_ws;

    // ---- workspace layout (float offsets) ----
    const size_t SZ_NODE  = (size_t)NN * 128;            // 6,400,000
    const size_t OFF_ITEM = 0;
    const size_t OFF_AG   = SZ_NODE;
    const size_t OFF_AG2  = 2 * SZ_NODE;
    const size_t OFF_LOW  = 3 * SZ_NODE;
    const size_t OFF_MID  = 4 * SZ_NODE;                 // big slab ends 32,000,000
    const size_t OFF_QKV2 = 0;                           // overlay (81920*384 = 31,457,280)
    const size_t OFF_GATH = 5 * SZ_NODE;                 // 49152*128 = 6,291,456
    const size_t OFF_H2   = OFF_GATH;                    // overlay (81920*128 = 10,485,760)
    const size_t OFF_QKV1 = OFF_GATH + 6291456;          // 49152*384 = 18,874,368
    const size_t OFF_H1   = OFF_QKV1 + 18874368;         // 81920*128 = 10,485,760
    const size_t OFF_CAT  = OFF_H1;                      // overlay (40960*128 = 5,242,880)
    size_t o = OFF_H1 + 10485760;
    short* WcT    = (short*)(ws + o);  o += 98304;       // 128x1536 bf16
    float* ptab2  = ws + o;            o += 12800;
    float* bias_c = ws + o;            o += 128;
    short* Wqkv1T = (short*)(ws + o);  o += 24576;       // 384x128 bf16
    float* bqkv1  = ws + o;            o += 384;
    short* Wqkv2T = (short*)(ws + o);  o += 24576;
    float* bqkv2  = ws + o;            o += 384;
    short* WlowT  = (short*)(ws + o);  o += 8192;
    short* WmidT  = (short*)(ws + o);  o += 8192;
    short* WcatT  = (short*)(ws + o);  o += 16384;       // 128x256 bf16
    float* stats  = ws + o;            o += 512;
    float* sb     = ws + o;            o += 512;
    float* scores = ws + o;            o += 20480;

    float* item = ws + OFF_ITEM;
    float* ag   = ws + OFF_AG;
    float* ag2  = ws + OFF_AG2;
    float* low  = ws + OFF_LOW;
    float* mid  = ws + OFF_MID;
    float* gath = ws + OFF_GATH;
    float* qkv1 = ws + OFF_QKV1;
    float* h1   = ws + OFF_H1;
    float* qkv2 = ws + OFF_QKV2;
    float* h2   = ws + OFF_H2;
    float* cat  = ws + OFF_CAT;

    // ---- weight packing ----
    hipLaunchKernelGGL(pack_wc,   dim3(1536), dim3(128), 0, stream, W_cid2, W_cid3, W_emb, WcT);
    hipLaunchKernelGGL(pack_ptab, dim3(100),  dim3(128), 0, stream, ptable, W_emb, ptab2);
    hipLaunchKernelGGL(pack_biasc,dim3(1),    dim3(128), 0, stream, b_cid2, b_cid3, b_emb, W_emb, bias_c);
    hipLaunchKernelGGL(pack_wt3,  dim3(128),  dim3(384), 0, stream, Wq1, Wk1, Wv1, bq1, bk1, bv1, Wqkv1T, bqkv1);
    hipLaunchKernelGGL(pack_wt3,  dim3(128),  dim3(384), 0, stream, Wq2, Wk2, Wv2, bq2, bk2, bv2, Wqkv2T, bqkv2);
    hipLaunchKernelGGL(pack_wt,   dim3(128),  dim3(128), 0, stream, W_low, WlowT, 128);
    hipLaunchKernelGGL(pack_wt,   dim3(128),  dim3(128), 0, stream, W_mid, WmidT, 128);
    hipLaunchKernelGGL(pack_wt,   dim3(256),  dim3(128), 0, stream, Wcat,  WcatT, 256);

    // ---- zero accumulators ----
    hipMemsetAsync(ag, 0, 2 * SZ_NODE * sizeof(float), stream);       // ag + ag2
    hipMemsetAsync(stats, 0, 512 * sizeof(float), stream);

    // ---- item = relu(features @ Wc + ptab2[price] + bias_c) ----
    hipLaunchKernelGGL((gemm_bf16<false, true, true>), dim3(391, 1), dim3(256), 0, stream,
                       features, nullptr, 1.f, 0.f, WcT, bias_c, price, ptab2,
                       item, 128, NN, 1536);

    // ---- ag = A @ item ; low = (0.5ag + 0.5item) @ W_low ----
    hipLaunchKernelGGL(spmm_kernel, dim3(1024), dim3(256), 0, stream,
                       adj_row, adj_col, adj_val, item, ag, EE);
    hipLaunchKernelGGL((gemm_bf16<true, false, false>), dim3(391, 1), dim3(256), 0, stream,
                       ag, item, 0.5f, 0.5f, WlowT, nullptr, nullptr, nullptr,
                       low, 128, NN, 128);

    // ---- ag2 = A @ ag ; mid = (0.5ag2 - 0.5item) @ W_mid ----
    hipLaunchKernelGGL(spmm_kernel, dim3(1024), dim3(256), 0, stream,
                       adj_row, adj_col, adj_val, ag, ag2, EE);
    hipLaunchKernelGGL((gemm_bf16<true, false, false>), dim3(391, 1), dim3(256), 0, stream,
                       ag2, item, 0.5f, -0.5f, WmidT, nullptr, nullptr, nullptr,
                       mid, 128, NN, 128);

    // ---- BN stats + fold to scale/shift ----
    hipLaunchKernelGGL(colstats, dim3(98, 2), dim3(256), 0, stream, low, mid, stats, NN);
    hipLaunchKernelGGL(bn_scalebias, dim3(1), dim3(256), 0, stream,
                       stats, bn1_g, bn1_b, bn2_g, bn2_b, sb, 1.f / (float)NN);

    // ---- gather + normalize: rows [key 8192 | pos 8192 | neg 32768] ----
    hipLaunchKernelGGL(gather_norm, dim3(4096),  dim3(256), 0, stream, low, mid, sb, train_set, gath,                 BQ, 0, 1);
    hipLaunchKernelGGL(gather_norm, dim3(4096),  dim3(256), 0, stream, low, mid, sb, train_set, gath + 8192*128,     BQ, 1, 1);
    hipLaunchKernelGGL(gather_norm, dim3(16384), dim3(256), 0, stream, low, mid, sb, train_set, gath + 16384*128,    BQ, 2, 4);

    // ---- layer-1 qkv (stacked) ----
    hipLaunchKernelGGL((gemm_bf16<false, false, false>), dim3(384, 3), dim3(256), 0, stream,
                       gath, nullptr, 1.f, 0.f, Wqkv1T, bqkv1, nullptr, nullptr,
                       qkv1, 384, 49152, 128);

    // ---- layer-1 attention (klp, pl, kln, nl) ----
    hipLaunchKernelGGL(attn_kernel, dim3(1024), dim3(256), 0, stream,
                       qkv1 + (size_t)8192*384, qkv1, h1, BQ, 0, 0);                       // klp
    hipLaunchKernelGGL(attn_kernel, dim3(1024), dim3(256), 0, stream,
                       qkv1, qkv1 + (size_t)8192*384, h1 + (size_t)8192*128, BQ, 0, 0);    // pl
    hipLaunchKernelGGL(attn_kernel, dim3(4096), dim3(256), 0, stream,
                       qkv1 + (size_t)16384*384, qkv1, h1 + (size_t)16384*128, BQ*NNEG, 0, 2); // kln
    hipLaunchKernelGGL(attn_kernel, dim3(4096), dim3(256), 0, stream,
                       qkv1, qkv1 + (size_t)16384*384, h1 + (size_t)49152*128, BQ*NNEG, 2, 0); // nl

    // ---- layer-2 qkv (stacked over all 4 flows) ----
    hipLaunchKernelGGL((gemm_bf16<false, false, false>), dim3(640, 3), dim3(256), 0, stream,
                       h1, nullptr, 1.f, 0.f, Wqkv2T, bqkv2, nullptr, nullptr,
                       qkv2, 384, 81920, 128);

    // ---- layer-2 attention ----
    const size_t rb[4] = { 0, 8192, 16384, 49152 };
    const int    nbs[4] = { BQ, BQ, BQ*NNEG, BQ*NNEG };
    for (int f = 0; f < 4; ++f) {
        hipLaunchKernelGGL(attn_kernel, dim3((nbs[f] + 3) / 4), dim3(256), 0, stream,
                           qkv2 + rb[f]*384, qkv2 + rb[f]*384, h2 + rb[f]*128, nbs[f], 0, 0);
    }

    // ---- cat = concat(h2[:,0],h2[:,1]) @ Wcat + bcat  (h2 viewed as rows of 256) ----
    hipLaunchKernelGGL((gemm_bf16<false, false, false>), dim3(320, 1), dim3(256), 0, stream,
                       h2, nullptr, 1.f, 0.f, WcatT, bcat, nullptr, nullptr,
                       cat, 128, 40960, 256);

    // ---- scores + loss ----
    hipLaunchKernelGGL(scores_kernel, dim3(5120), dim3(256), 0, stream, cat, scores);
    hipLaunchKernelGGL(loss_kernel, dim3(1), dim3(256), 0, stream, scores, (float*)d_out);
}

// Round 2
// 1293.227 us; speedup vs baseline: 2.7218x; 2.7218x over previous
//
#include <hip/hip_runtime.h>
#include <hip/hip_bf16.h>

// ---------------------------------------------------------------------------
// SComGNN: item GEMM -> CSR build -> spmm x2 (gather) -> low/mid GEMM ->
// BN stats -> gather-norm -> qkv GEMM -> attn -> qkv GEMM -> attn -> Wcat -> loss
// ---------------------------------------------------------------------------

typedef __attribute__((ext_vector_type(4))) float  f32x4;
typedef __attribute__((ext_vector_type(2))) float  f32x2;
typedef __attribute__((ext_vector_type(8))) short  s16x8;
typedef __attribute__((ext_vector_type(4))) short  s16x4;
typedef __attribute__((ext_vector_type(8))) __bf16 bf16x8;

#define NN   50000
#define EE   1600000
#define BQ   4096
#define NNEG 4

__device__ __forceinline__ short f2b(float x) {
    union { float f; unsigned u; } c; c.f = x;
    unsigned r = c.u + 0x7FFF + ((c.u >> 16) & 1);   // RNE to bf16
    return (short)(r >> 16);
}

// ---------------------------------------------------------------------------
// Generic 128-col-tile bf16 MFMA GEMM (unchanged from R0)
// ---------------------------------------------------------------------------
template<bool TWOSRC, bool PRICE, bool RELU>
__global__ __launch_bounds__(256)
void gemm_bf16(const float* __restrict__ A1, const float* __restrict__ A2,
               float alpha, float beta,
               const short* __restrict__ WT, const float* __restrict__ bias,
               const int* __restrict__ price, const float* __restrict__ ptab,
               float* __restrict__ Y, int ldY, int rows, int K)
{
    __shared__ short Alds[128][32];
    __shared__ short Wlds[128][32];

    const int t    = threadIdx.x;
    const int lane = t & 63;
    const int w    = t >> 6;
    const int r0   = blockIdx.x * 128;
    const int c0   = blockIdx.y * 128;
    const short* WTb = WT + (size_t)c0 * K;

    f32x4 acc[4][4];
#pragma unroll
    for (int m = 0; m < 4; ++m)
#pragma unroll
        for (int n = 0; n < 4; ++n) acc[m][n] = (f32x4)0.f;

    const int srow = t >> 3;
    const int skk  = (t & 7) * 4;
    const int wn   = t >> 1;
    const int wkp  = (t & 1) * 16;

    const int wr   = (w >> 1) * 64;
    const int wc   = (w & 1) * 64;
    const int rsel = lane & 15;
    const int kb   = (lane >> 4) * 8;

    for (int k0 = 0; k0 < K; k0 += 32) {
#pragma unroll
        for (int i = 0; i < 4; ++i) {
            int r  = srow + i * 32;
            int rg = r0 + r; rg = rg < rows ? rg : rows - 1;
            float4 va = *(const float4*)(A1 + (size_t)rg * K + (k0 + skk));
            if (TWOSRC) {
                float4 vb = *(const float4*)(A2 + (size_t)rg * K + (k0 + skk));
                va.x = alpha * va.x + beta * vb.x;
                va.y = alpha * va.y + beta * vb.y;
                va.z = alpha * va.z + beta * vb.z;
                va.w = alpha * va.w + beta * vb.w;
            }
            s16x4 sv; sv[0]=f2b(va.x); sv[1]=f2b(va.y); sv[2]=f2b(va.z); sv[3]=f2b(va.w);
            int sw = ((r >> 1) & 3) * 8;
            *(s16x4*)&Alds[r][skk ^ sw] = sv;
        }
        {
            const short* p = WTb + (size_t)wn * K + (k0 + wkp);
            s16x8 w0 = *(const s16x8*)p;
            s16x8 w1 = *(const s16x8*)(p + 8);
            int sw = ((wn >> 1) & 3) * 8;
            *(s16x8*)&Wlds[wn][wkp ^ sw]       = w0;
            *(s16x8*)&Wlds[wn][(wkp + 8) ^ sw] = w1;
        }
        __syncthreads();

        s16x8 af[4], bfr[4];
#pragma unroll
        for (int m = 0; m < 4; ++m) {
            int r = wr + m * 16 + rsel;
            af[m] = *(const s16x8*)&Alds[r][kb ^ (((r >> 1) & 3) * 8)];
        }
#pragma unroll
        for (int n = 0; n < 4; ++n) {
            int r = wc + n * 16 + rsel;
            bfr[n] = *(const s16x8*)&Wlds[r][kb ^ (((r >> 1) & 3) * 8)];
        }
#pragma unroll
        for (int m = 0; m < 4; ++m)
#pragma unroll
            for (int n = 0; n < 4; ++n)
                acc[m][n] = __builtin_amdgcn_mfma_f32_16x16x32_bf16(
                    __builtin_bit_cast(bf16x8, af[m]),
                    __builtin_bit_cast(bf16x8, bfr[n]), acc[m][n], 0, 0, 0);
        __syncthreads();
    }

    const int crow = (lane >> 4) * 4;
#pragma unroll
    for (int m = 0; m < 4; ++m) {
        int rbase = r0 + wr + m * 16 + crow;
#pragma unroll
        for (int i = 0; i < 4; ++i) {
            int gr = rbase + i;
            bool ok = (gr < rows);
            int pidx = 0;
            if (PRICE) pidx = ok ? price[gr] : 0;
#pragma unroll
            for (int n = 0; n < 4; ++n) {
                int coll = wc + n * 16 + rsel;
                int cc   = c0 + coll;
                float v  = acc[m][n][i];
                if (bias)  v += bias[cc];
                if (PRICE) v += ptab[pidx * 128 + coll];
                if (RELU)  v = fmaxf(v, 0.f);
                if (ok) Y[(size_t)gr * ldY + cc] = v;
            }
        }
    }
}

// ---------------------------------------------------------------------------
// CSR build: hist -> scan (3 kernels) -> scatter
// ---------------------------------------------------------------------------
__global__ __launch_bounds__(256)
void hist_rows(const int* __restrict__ row, int* __restrict__ cnt)
{
    int e = blockIdx.x * 256 + threadIdx.x;
    if (e < EE) atomicAdd(&cnt[row[e]], 1);
}

__global__ __launch_bounds__(1024)
void scan_a(const int* __restrict__ cnt, int* __restrict__ rp, int* __restrict__ bsum)
{
    __shared__ int tmp[1024];
    int t = threadIdx.x, g = blockIdx.x * 1024 + t;
    int v = (g < NN) ? cnt[g] : 0;
    tmp[t] = v;
    __syncthreads();
    for (int off = 1; off < 1024; off <<= 1) {
        int a = (t >= off) ? tmp[t - off] : 0;
        __syncthreads();
        tmp[t] += a;
        __syncthreads();
    }
    if (g < NN) rp[g] = tmp[t] - v;          // local exclusive
    if (t == 1023) bsum[blockIdx.x] = tmp[t];
}

__global__ void scan_b(int* __restrict__ bsum, int nb)
{
    if (threadIdx.x == 0) {
        int acc = 0;
        for (int i = 0; i < nb; ++i) { int v = bsum[i]; bsum[i] = acc; acc += v; }
    }
}

__global__ __launch_bounds__(1024)
void scan_c(int* __restrict__ rp, int* __restrict__ cur, const int* __restrict__ bsum)
{
    int t = threadIdx.x, g = blockIdx.x * 1024 + t;
    if (g < NN) {
        int v = rp[g] + bsum[blockIdx.x];
        rp[g] = v; cur[g] = v;
    }
    if (g == 0) rp[NN] = EE;
}

__global__ __launch_bounds__(256)
void scatter_edges(const int* __restrict__ row, const int* __restrict__ col,
                   const float* __restrict__ val, int* __restrict__ cur,
                   int* __restrict__ pcol, float* __restrict__ pval)
{
    int e = blockIdx.x * 256 + threadIdx.x;
    if (e >= EE) return;
    int p = atomicAdd(&cur[row[e]], 1);
    pcol[p] = col[e];
    pval[p] = val[e];
}

// ---------------------------------------------------------------------------
// CSR SpMM: one wave per row, register accumulate, single coalesced store.
// ---------------------------------------------------------------------------
__global__ __launch_bounds__(256)
void spmm_csr(const int* __restrict__ rp, const int* __restrict__ pcol,
              const float* __restrict__ pval, const float* __restrict__ x,
              float* __restrict__ y)
{
    int w    = (blockIdx.x * 256 + threadIdx.x) >> 6;
    int lane = threadIdx.x & 63;
    if (w >= NN) return;
    int s = rp[w], e = rp[w + 1];
    int d = lane * 2;
    float ax = 0.f, ay = 0.f;
    int i = s;
    for (; i + 2 <= e; i += 2) {
        int   c0 = pcol[i],   c1 = pcol[i + 1];
        float v0 = pval[i],   v1 = pval[i + 1];
        f32x2 x0 = *(const f32x2*)(x + (size_t)c0 * 128 + d);
        f32x2 x1 = *(const f32x2*)(x + (size_t)c1 * 128 + d);
        ax += v0 * x0.x + v1 * x1.x;
        ay += v0 * x0.y + v1 * x1.y;
    }
    if (i < e) {
        int c0 = pcol[i]; float v0 = pval[i];
        f32x2 x0 = *(const f32x2*)(x + (size_t)c0 * 128 + d);
        ax += v0 * x0.x; ay += v0 * x0.y;
    }
    f32x2 r; r.x = ax; r.y = ay;
    *(f32x2*)(y + (size_t)w * 128 + d) = r;
}

// ---------------------------------------------------------------------------
// Column stats / BN fold / gather-norm (unchanged)
// ---------------------------------------------------------------------------
__global__ __launch_bounds__(256)
void colstats(const float* __restrict__ low, const float* __restrict__ mid,
              float* __restrict__ stats, int nrows)
{
    const float* src = blockIdx.y ? mid : low;
    int c = threadIdx.x & 127;
    int h = threadIdx.x >> 7;
    int rs = blockIdx.x * 512;
    int re = min(rs + 512, nrows);
    float s1 = 0.f, s2 = 0.f;
    for (int r = rs + h; r < re; r += 2) {
        float xv = src[(size_t)r * 128 + c];
        s1 += xv; s2 += xv * xv;
    }
    __shared__ float l1[256], l2[256];
    l1[threadIdx.x] = s1; l2[threadIdx.x] = s2;
    __syncthreads();
    if (h == 0) {
        s1 = l1[c] + l1[128 + c];
        s2 = l2[c] + l2[128 + c];
        atomicAdd(&stats[blockIdx.y * 256 + c],       s1);
        atomicAdd(&stats[blockIdx.y * 256 + 128 + c], s2);
    }
}

__global__ __launch_bounds__(256)
void bn_scalebias(const float* __restrict__ stats,
                  const float* g1, const float* b1,
                  const float* g2, const float* b2,
                  float* __restrict__ sb, float inv_n)
{
    int t = threadIdx.x;
    int mat = t >> 7, c = t & 127;
    float mean = stats[mat * 256 + c] * inv_n;
    float var  = stats[mat * 256 + 128 + c] * inv_n - mean * mean;
    float s = (mat ? g2[c] : g1[c]) * rsqrtf(var + 1e-5f);
    float tt = (mat ? b2[c] : b1[c]) - mean * s;
    sb[mat * 256 + c] = s;
    sb[mat * 256 + 128 + c] = tt;
}

__global__ __launch_bounds__(256)
void gather_norm(const float* __restrict__ low, const float* __restrict__ mid,
                 const float* __restrict__ sb, const int* __restrict__ ts,
                 float* __restrict__ out, int nb, int slot0, int nslots)
{
    int idx = blockIdx.x * 256 + threadIdx.x;
    if (idx >= nb * nslots * 256) return;
    int c   = idx & 127;
    int seq = (idx >> 7) & 1;
    int r   = idx >> 8;
    int b = r / nslots, j = r - b * nslots;
    int node = ts[b * 6 + slot0 + j];
    const float* src = seq ? mid : low;
    float xv = src[(size_t)node * 128 + c];
    out[(size_t)r * 256 + seq * 128 + c] = xv * sb[seq * 256 + c] + sb[seq * 256 + 128 + c];
}

// ---------------------------------------------------------------------------
// 2-token attention, softmax over axis=1 (queries)
// ---------------------------------------------------------------------------
__global__ __launch_bounds__(256)
void attn_kernel(const float* __restrict__ qbase, const float* __restrict__ kvbase,
                 float* __restrict__ h, int nb, int qshift, int kvshift)
{
    int gw   = (blockIdx.x * 256 + threadIdx.x) >> 6;
    int lane = threadIdx.x & 63;
    if (gw >= nb) return;
    int qb = (gw >> qshift) * 2;
    int kb = (gw >> kvshift) * 2;
    const float* q0 = qbase + (size_t)qb * 384;
    const float* q1 = q0 + 384;
    const float* k0 = kvbase + (size_t)kb * 384 + 128;
    const float* k1 = k0 + 384;
    const float* v0 = kvbase + (size_t)kb * 384 + 256;
    const float* v1 = v0 + 384;
    int d = lane * 2;
    f32x2 q0v = *(const f32x2*)(q0 + d);
    f32x2 q1v = *(const f32x2*)(q1 + d);
    f32x2 k0v = *(const f32x2*)(k0 + d);
    f32x2 k1v = *(const f32x2*)(k1 + d);
    float s00 = q0v.x*k0v.x + q0v.y*k0v.y;
    float s01 = q0v.x*k1v.x + q0v.y*k1v.y;
    float s10 = q1v.x*k0v.x + q1v.y*k0v.y;
    float s11 = q1v.x*k1v.x + q1v.y*k1v.y;
#pragma unroll
    for (int off = 32; off; off >>= 1) {
        s00 += __shfl_xor(s00, off);
        s01 += __shfl_xor(s01, off);
        s10 += __shfl_xor(s10, off);
        s11 += __shfl_xor(s11, off);
    }
    const float scale = 0.08838834764831845f;
    s00 *= scale; s01 *= scale; s10 *= scale; s11 *= scale;
    float m0 = fmaxf(s00, s10), m1 = fmaxf(s01, s11);
    float e00 = __expf(s00 - m0), e10 = __expf(s10 - m0);
    float e01 = __expf(s01 - m1), e11 = __expf(s11 - m1);
    float i0 = 1.f / (e00 + e10), i1 = 1.f / (e01 + e11);
    float a00 = e00 * i0, a10 = e10 * i0;
    float a01 = e01 * i1, a11 = e11 * i1;
    f32x2 v0v = *(const f32x2*)(v0 + d);
    f32x2 v1v = *(const f32x2*)(v1 + d);
    f32x2 h0, h1;
    h0.x = a00*v0v.x + a01*v1v.x;  h0.y = a00*v0v.y + a01*v1v.y;
    h1.x = a10*v0v.x + a11*v1v.x;  h1.y = a10*v0v.y + a11*v1v.y;
    *(f32x2*)(h + (size_t)(gw * 2)     * 128 + d) = h0;
    *(f32x2*)(h + (size_t)(gw * 2 + 1) * 128 + d) = h1;
}

// ---------------------------------------------------------------------------
__global__ __launch_bounds__(256)
void scores_kernel(const float* __restrict__ cat, float* __restrict__ scores)
{
    int gw   = (blockIdx.x * 256 + threadIdx.x) >> 6;
    int lane = threadIdx.x & 63;
    if (gw >= 20480) return;
    const float *pa, *pb;
    if (gw < BQ) { pa = cat + (size_t)gw * 128;            pb = cat + (size_t)(BQ + gw) * 128; }
    else { int n = gw - BQ; pa = cat + (size_t)(2*BQ + n) * 128; pb = cat + (size_t)(2*BQ + BQ*NNEG + n) * 128; }
    f32x2 a = *(const f32x2*)(pa + lane * 2);
    f32x2 b = *(const f32x2*)(pb + lane * 2);
    float s = a.x * b.x + a.y * b.y;
#pragma unroll
    for (int off = 32; off; off >>= 1) s += __shfl_xor(s, off);
    if (lane == 0) scores[gw] = s;
}

__global__ __launch_bounds__(256)
void loss_kernel(const float* __restrict__ scores, float* __restrict__ out)
{
    int t = threadIdx.x;
    float acc = 0.f;
    for (int i = t; i < BQ * NNEG; i += 256) {
        int b = i >> 2;
        float x = scores[b] - scores[BQ + i];
        float sig = 1.f / (1.f + __expf(-x));
        acc += __logf(sig + 1e-9f);
    }
    __shared__ float red[256];
    red[t] = acc; __syncthreads();
    for (int s = 128; s > 0; s >>= 1) { if (t < s) red[t] += red[t + s]; __syncthreads(); }
    if (t == 0) out[0] = -red[0] / (float)(BQ * NNEG);
}

// ---------------------------------------------------------------------------
// Weight-pack kernels
// ---------------------------------------------------------------------------
__global__ void pack_wc(const float* __restrict__ W2, const float* __restrict__ W3,
                        const float* __restrict__ We, short* __restrict__ WcT)
{
    int k = blockIdx.x, n = threadIdx.x;
    const float* Wrow = (k < 768) ? (W2 + (size_t)k * 128) : (W3 + (size_t)(k - 768) * 128);
    const float* Web  = We + ((k < 768) ? 0 : 128 * 128);
    float acc = 0.f;
    for (int j = 0; j < 128; ++j) acc += Wrow[j] * Web[j * 128 + n];
    WcT[(size_t)n * 1536 + k] = f2b(acc);
}

__global__ void pack_ptab(const float* __restrict__ PT, const float* __restrict__ We,
                          float* __restrict__ ptab2)
{
    int p = blockIdx.x, n = threadIdx.x;
    const float* Web = We + 256 * 128;
    float acc = 0.f;
    for (int j = 0; j < 128; ++j) acc += PT[p * 128 + j] * Web[j * 128 + n];
    ptab2[p * 128 + n] = acc;
}

__global__ void pack_biasc(const float* b2, const float* b3, const float* bemb,
                           const float* __restrict__ We, float* __restrict__ bias_c)
{
    int n = threadIdx.x;
    float acc = bemb[n];
    for (int j = 0; j < 128; ++j)
        acc += b2[j] * We[j * 128 + n] + b3[j] * We[(128 + j) * 128 + n];
    bias_c[n] = acc;
}

__global__ void pack_wt(const float* __restrict__ W, short* __restrict__ WT, int K)
{
    int k = blockIdx.x, n = threadIdx.x;
    WT[(size_t)n * K + k] = f2b(W[(size_t)k * 128 + n]);
}

__global__ void pack_wt3(const float* Wq, const float* Wk, const float* Wv,
                         const float* bq, const float* bk, const float* bv,
                         short* __restrict__ WT, float* __restrict__ bout)
{
    int k = blockIdx.x, n = threadIdx.x;
    const float* W = (n < 128) ? Wq : ((n < 256) ? Wk : Wv);
    int nl = n & 127;
    WT[(size_t)n * 128 + k] = f2b(W[k * 128 + nl]);
    if (k == 0) {
        const float* b = (n < 128) ? bq : ((n < 256) ? bk : bv);
        bout[n] = b[nl];
    }
}

// ---------------------------------------------------------------------------
extern "C" void kernel_launch(void* const* d_in, const int* in_sizes, int n_in,
                              void* d_out, int out_size, void* d_ws, size_t ws_size,
                              hipStream_t stream)
{
    const float* features = (const float*)d_in[0];
    const int*   price    = (const int*)  d_in[1];
    const int*   adj_row  = (const int*)  d_in[2];
    const int*   adj_col  = (const int*)  d_in[3];
    const float* adj_val  = (const float*)d_in[4];
    const int*   train_set= (const int*)  d_in[5];
    const float* W_cid2   = (const float*)d_in[6];
    const float* b_cid2   = (const float*)d_in[7];
    const float* W_cid3   = (const float*)d_in[8];
    const float* b_cid3   = (const float*)d_in[9];
    const float* ptable   = (const float*)d_in[10];
    const float* W_emb    = (const float*)d_in[11];
    const float* b_emb    = (const float*)d_in[12];
    const float* W_low    = (const float*)d_in[13];
    const float* W_mid    = (const float*)d_in[14];
    const float* bn1_g    = (const float*)d_in[15];
    const float* bn1_b    = (const float*)d_in[16];
    const float* bn2_g    = (const float*)d_in[17];
    const float* bn2_b    = (const float*)d_in[18];
    const float* Wq1 = (const float*)d_in[19]; const float* bq1 = (const float*)d_in[20];
    const float* Wk1 = (const float*)d_in[21]; const float* bk1 = (const float*)d_in[22];
    const float* Wv1 = (const float*)d_in[23]; const float* bv1 = (const float*)d_in[24];
    const float* Wq2 = (const float*)d_in[25]; const float* bq2 = (const float*)d_in[26];
    const float* Wk2 = (const float*)d_in[27]; const float* bk2 = (const float*)d_in[28];
    const float* Wv2 = (const float*)d_in[29]; const float* bv2 = (const float*)d_in[30];
    const float* Wcat= (const float*)d_in[31]; const float* bcat= (const float*)d_in[32];

    float* ws = (float*)d_ws;

    // ---- workspace layout (float offsets) ----
    const size_t SZ_NODE  = (size_t)NN * 128;            // 6,400,000
    const size_t OFF_ITEM = 0;
    const size_t OFF_AG   = SZ_NODE;
    const size_t OFF_AG2  = 2 * SZ_NODE;
    const size_t OFF_LOW  = 3 * SZ_NODE;
    const size_t OFF_MID  = 4 * SZ_NODE;
    const size_t OFF_QKV2 = 0;                           // overlay
    const size_t OFF_GATH = 5 * SZ_NODE;                 // 49152*128
    const size_t OFF_H2   = OFF_GATH;                    // overlay
    const size_t OFF_QKV1 = OFF_GATH + 6291456;
    const size_t OFF_H1   = OFF_QKV1 + 18874368;
    const size_t OFF_CAT  = OFF_H1;                      // overlay
    size_t o = OFF_H1 + 10485760;
    short* WcT    = (short*)(ws + o);  o += 98304;
    float* ptab2  = ws + o;            o += 12800;
    float* bias_c = ws + o;            o += 128;
    short* Wqkv1T = (short*)(ws + o);  o += 24576;
    float* bqkv1  = ws + o;            o += 384;
    short* Wqkv2T = (short*)(ws + o);  o += 24576;
    float* bqkv2  = ws + o;            o += 384;
    short* WlowT  = (short*)(ws + o);  o += 8192;
    short* WmidT  = (short*)(ws + o);  o += 8192;
    short* WcatT  = (short*)(ws + o);  o += 16384;
    float* stats  = ws + o;            o += 512;
    float* sb     = ws + o;            o += 512;
    float* scores = ws + o;            o += 20480;

    float* item = ws + OFF_ITEM;
    float* ag   = ws + OFF_AG;
    float* ag2  = ws + OFF_AG2;
    float* low  = ws + OFF_LOW;
    float* mid  = ws + OFF_MID;
    float* gath = ws + OFF_GATH;
    float* qkv1 = ws + OFF_QKV1;
    float* h1   = ws + OFF_H1;
    float* qkv2 = ws + OFF_QKV2;
    float* h2   = ws + OFF_H2;
    float* cat  = ws + OFF_CAT;

    // CSR arrays overlay the gath region (dead until after spmm2).
    int*   rp   = (int*)(ws + OFF_GATH);     // 50001
    int*   cur  = rp + 50008;                // 50000 (also used as cnt)
    int*   bsum = cur + 50008;               // 64
    int*   pcol = bsum + 64 + 56;            // 1,600,000  (16B aligned)
    float* pval = (float*)(pcol + 1600000);  // 1,600,000

    // ---- weight packing ----
    hipLaunchKernelGGL(pack_wc,   dim3(1536), dim3(128), 0, stream, W_cid2, W_cid3, W_emb, WcT);
    hipLaunchKernelGGL(pack_ptab, dim3(100),  dim3(128), 0, stream, ptable, W_emb, ptab2);
    hipLaunchKernelGGL(pack_biasc,dim3(1),    dim3(128), 0, stream, b_cid2, b_cid3, b_emb, W_emb, bias_c);
    hipLaunchKernelGGL(pack_wt3,  dim3(128),  dim3(384), 0, stream, Wq1, Wk1, Wv1, bq1, bk1, bv1, Wqkv1T, bqkv1);
    hipLaunchKernelGGL(pack_wt3,  dim3(128),  dim3(384), 0, stream, Wq2, Wk2, Wv2, bq2, bk2, bv2, Wqkv2T, bqkv2);
    hipLaunchKernelGGL(pack_wt,   dim3(128),  dim3(128), 0, stream, W_low, WlowT, 128);
    hipLaunchKernelGGL(pack_wt,   dim3(128),  dim3(128), 0, stream, W_mid, WmidT, 128);
    hipLaunchKernelGGL(pack_wt,   dim3(256),  dim3(128), 0, stream, Wcat,  WcatT, 256);

    hipMemsetAsync(stats, 0, 512 * sizeof(float), stream);
    hipMemsetAsync(cur, 0, 50000 * sizeof(int), stream);

    // ---- CSR build (once; same adjacency for both spmms) ----
    hipLaunchKernelGGL(hist_rows,     dim3(6250), dim3(256),  0, stream, adj_row, cur);
    hipLaunchKernelGGL(scan_a,        dim3(49),   dim3(1024), 0, stream, cur, rp, bsum);
    hipLaunchKernelGGL(scan_b,        dim3(1),    dim3(64),   0, stream, bsum, 49);
    hipLaunchKernelGGL(scan_c,        dim3(49),   dim3(1024), 0, stream, rp, cur, bsum);
    hipLaunchKernelGGL(scatter_edges, dim3(6250), dim3(256),  0, stream,
                       adj_row, adj_col, adj_val, cur, pcol, pval);

    // ---- item = relu(features @ Wc + ptab2[price] + bias_c) ----
    hipLaunchKernelGGL((gemm_bf16<false, true, true>), dim3(391, 1), dim3(256), 0, stream,
                       features, nullptr, 1.f, 0.f, WcT, bias_c, price, ptab2,
                       item, 128, NN, 1536);

    // ---- ag = A @ item ; low = (0.5ag + 0.5item) @ W_low ----
    hipLaunchKernelGGL(spmm_csr, dim3(12500), dim3(256), 0, stream, rp, pcol, pval, item, ag);
    hipLaunchKernelGGL((gemm_bf16<true, false, false>), dim3(391, 1), dim3(256), 0, stream,
                       ag, item, 0.5f, 0.5f, WlowT, nullptr, nullptr, nullptr,
                       low, 128, NN, 128);

    // ---- ag2 = A @ ag ; mid = (0.5ag2 - 0.5item) @ W_mid ----
    hipLaunchKernelGGL(spmm_csr, dim3(12500), dim3(256), 0, stream, rp, pcol, pval, ag, ag2);
    hipLaunchKernelGGL((gemm_bf16<true, false, false>), dim3(391, 1), dim3(256), 0, stream,
                       ag2, item, 0.5f, -0.5f, WmidT, nullptr, nullptr, nullptr,
                       mid, 128, NN, 128);

    // ---- BN stats + fold ----
    hipLaunchKernelGGL(colstats, dim3(98, 2), dim3(256), 0, stream, low, mid, stats, NN);
    hipLaunchKernelGGL(bn_scalebias, dim3(1), dim3(256), 0, stream,
                       stats, bn1_g, bn1_b, bn2_g, bn2_b, sb, 1.f / (float)NN);

    // ---- gather + normalize (CSR arrays dead from here; gath overlays them) ----
    hipLaunchKernelGGL(gather_norm, dim3(4096),  dim3(256), 0, stream, low, mid, sb, train_set, gath,              BQ, 0, 1);
    hipLaunchKernelGGL(gather_norm, dim3(4096),  dim3(256), 0, stream, low, mid, sb, train_set, gath + 8192*128,   BQ, 1, 1);
    hipLaunchKernelGGL(gather_norm, dim3(16384), dim3(256), 0, stream, low, mid, sb, train_set, gath + 16384*128,  BQ, 2, 4);

    // ---- layer-1 qkv (stacked) ----
    hipLaunchKernelGGL((gemm_bf16<false, false, false>), dim3(384, 3), dim3(256), 0, stream,
                       gath, nullptr, 1.f, 0.f, Wqkv1T, bqkv1, nullptr, nullptr,
                       qkv1, 384, 49152, 128);

    // ---- layer-1 attention ----
    hipLaunchKernelGGL(attn_kernel, dim3(1024), dim3(256), 0, stream,
                       qkv1 + (size_t)8192*384, qkv1, h1, BQ, 0, 0);
    hipLaunchKernelGGL(attn_kernel, dim3(1024), dim3(256), 0, stream,
                       qkv1, qkv1 + (size_t)8192*384, h1 + (size_t)8192*128, BQ, 0, 0);
    hipLaunchKernelGGL(attn_kernel, dim3(4096), dim3(256), 0, stream,
                       qkv1 + (size_t)16384*384, qkv1, h1 + (size_t)16384*128, BQ*NNEG, 0, 2);
    hipLaunchKernelGGL(attn_kernel, dim3(4096), dim3(256), 0, stream,
                       qkv1, qkv1 + (size_t)16384*384, h1 + (size_t)49152*128, BQ*NNEG, 2, 0);

    // ---- layer-2 qkv ----
    hipLaunchKernelGGL((gemm_bf16<false, false, false>), dim3(640, 3), dim3(256), 0, stream,
                       h1, nullptr, 1.f, 0.f, Wqkv2T, bqkv2, nullptr, nullptr,
                       qkv2, 384, 81920, 128);

    // ---- layer-2 attention ----
    const size_t rb[4] = { 0, 8192, 16384, 49152 };
    const int    nbs[4] = { BQ, BQ, BQ*NNEG, BQ*NNEG };
    for (int f = 0; f < 4; ++f) {
        hipLaunchKernelGGL(attn_kernel, dim3((nbs[f] + 3) / 4), dim3(256), 0, stream,
                           qkv2 + rb[f]*384, qkv2 + rb[f]*384, h2 + rb[f]*128, nbs[f], 0, 0);
    }

    // ---- cat GEMM ----
    hipLaunchKernelGGL((gemm_bf16<false, false, false>), dim3(320, 1), dim3(256), 0, stream,
                       h2, nullptr, 1.f, 0.f, WcatT, bcat, nullptr, nullptr,
                       cat, 128, 40960, 256);

    // ---- scores + loss ----
    hipLaunchKernelGGL(scores_kernel, dim3(5120), dim3(256), 0, stream, cat, scores);
    hipLaunchKernelGGL(loss_kernel, dim3(1), dim3(256), 0, stream, scores, (float*)d_out);
}

// Round 6
// 1122.800 us; speedup vs baseline: 3.1349x; 1.1518x over previous
//
#include <hip/hip_runtime.h>
#include <hip/hip_bf16.h>

// ---------------------------------------------------------------------------
// SComGNN: item GEMM -> CSR build -> spmm x2 (bf16 gather) -> low/mid GEMM ->
// BN -> gather-norm(bf16) -> qkv GEMM -> attn -> qkv GEMM -> attn -> cat -> loss
// ---------------------------------------------------------------------------

typedef __attribute__((ext_vector_type(4))) float  f32x4;
typedef __attribute__((ext_vector_type(2))) float  f32x2;
typedef __attribute__((ext_vector_type(8))) short  s16x8;
typedef __attribute__((ext_vector_type(4))) short  s16x4;
typedef __attribute__((ext_vector_type(8))) __bf16 bf16x8;

#define NN   50000
#define EE   1600000
#define BQ   4096
#define NNEG 4

__device__ __forceinline__ short f2b(float x) {
    union { float f; unsigned u; } c; c.f = x;
    unsigned r = c.u + 0x7FFF + ((c.u >> 16) & 1);   // RNE to bf16
    return (short)(r >> 16);
}
__device__ __forceinline__ float blo(unsigned u) { return __builtin_bit_cast(float, u << 16); }
__device__ __forceinline__ float bhi(unsigned u) { return __builtin_bit_cast(float, u & 0xffff0000u); }
__device__ __forceinline__ unsigned pk2(float a, float b) {
    return (unsigned)(unsigned short)f2b(a) | ((unsigned)(unsigned short)f2b(b) << 16);
}

// ---------------------------------------------------------------------------
// f32-A MFMA GEMM (128x128 tile). OUTBF: additionally write bf16 copy Yb.
// ---------------------------------------------------------------------------
template<bool TWOSRC, bool PRICE, bool RELU, bool OUTBF>
__global__ __launch_bounds__(256)
void gemm_bf16(const float* __restrict__ A1, const float* __restrict__ A2,
               float alpha, float beta,
               const short* __restrict__ WT, const float* __restrict__ bias,
               const int* __restrict__ price, const float* __restrict__ ptab,
               float* __restrict__ Y, unsigned short* __restrict__ Yb,
               int ldY, int rows, int K)
{
    __shared__ short Alds[128][32];
    __shared__ short Wlds[128][32];

    const int t    = threadIdx.x;
    const int lane = t & 63;
    const int w    = t >> 6;
    const int r0   = blockIdx.x * 128;
    const int c0   = blockIdx.y * 128;
    const short* WTb = WT + (size_t)c0 * K;

    f32x4 acc[4][4];
#pragma unroll
    for (int m = 0; m < 4; ++m)
#pragma unroll
        for (int n = 0; n < 4; ++n) acc[m][n] = (f32x4)0.f;

    const int srow = t >> 3;
    const int skk  = (t & 7) * 4;
    const int wn   = t >> 1;
    const int wkp  = (t & 1) * 16;

    const int wr   = (w >> 1) * 64;
    const int wc   = (w & 1) * 64;
    const int rsel = lane & 15;
    const int kb   = (lane >> 4) * 8;

    for (int k0 = 0; k0 < K; k0 += 32) {
#pragma unroll
        for (int i = 0; i < 4; ++i) {
            int r  = srow + i * 32;
            int rg = r0 + r; rg = rg < rows ? rg : rows - 1;
            float4 va = *(const float4*)(A1 + (size_t)rg * K + (k0 + skk));
            if (TWOSRC) {
                float4 vb = *(const float4*)(A2 + (size_t)rg * K + (k0 + skk));
                va.x = alpha * va.x + beta * vb.x;
                va.y = alpha * va.y + beta * vb.y;
                va.z = alpha * va.z + beta * vb.z;
                va.w = alpha * va.w + beta * vb.w;
            }
            s16x4 sv; sv[0]=f2b(va.x); sv[1]=f2b(va.y); sv[2]=f2b(va.z); sv[3]=f2b(va.w);
            int sw = ((r >> 1) & 3) * 8;
            *(s16x4*)&Alds[r][skk ^ sw] = sv;
        }
        {
            const short* p = WTb + (size_t)wn * K + (k0 + wkp);
            s16x8 w0 = *(const s16x8*)p;
            s16x8 w1 = *(const s16x8*)(p + 8);
            int sw = ((wn >> 1) & 3) * 8;
            *(s16x8*)&Wlds[wn][wkp ^ sw]       = w0;
            *(s16x8*)&Wlds[wn][(wkp + 8) ^ sw] = w1;
        }
        __syncthreads();

        s16x8 af[4], bfr[4];
#pragma unroll
        for (int m = 0; m < 4; ++m) {
            int r = wr + m * 16 + rsel;
            af[m] = *(const s16x8*)&Alds[r][kb ^ (((r >> 1) & 3) * 8)];
        }
#pragma unroll
        for (int n = 0; n < 4; ++n) {
            int r = wc + n * 16 + rsel;
            bfr[n] = *(const s16x8*)&Wlds[r][kb ^ (((r >> 1) & 3) * 8)];
        }
#pragma unroll
        for (int m = 0; m < 4; ++m)
#pragma unroll
            for (int n = 0; n < 4; ++n)
                acc[m][n] = __builtin_amdgcn_mfma_f32_16x16x32_bf16(
                    __builtin_bit_cast(bf16x8, af[m]),
                    __builtin_bit_cast(bf16x8, bfr[n]), acc[m][n], 0, 0, 0);
        __syncthreads();
    }

    const int crow = (lane >> 4) * 4;
#pragma unroll
    for (int m = 0; m < 4; ++m) {
        int rbase = r0 + wr + m * 16 + crow;
#pragma unroll
        for (int i = 0; i < 4; ++i) {
            int gr = rbase + i;
            bool ok = (gr < rows);
            int pidx = 0;
            if (PRICE) pidx = ok ? price[gr] : 0;
#pragma unroll
            for (int n = 0; n < 4; ++n) {
                int coll = wc + n * 16 + rsel;
                int cc   = c0 + coll;
                float v  = acc[m][n][i];
                if (bias)  v += bias[cc];
                if (PRICE) v += ptab[pidx * 128 + coll];
                if (RELU)  v = fmaxf(v, 0.f);
                if (ok) {
                    Y[(size_t)gr * ldY + cc] = v;
                    if (OUTBF) Yb[(size_t)gr * ldY + cc] = (unsigned short)f2b(v);
                }
            }
        }
    }
}

// ---------------------------------------------------------------------------
// bf16-A MFMA GEMM (single source), bias optional; OUTBF selects output fmt.
// ---------------------------------------------------------------------------
template<bool OUTBF>
__global__ __launch_bounds__(256)
void gemm_a16(const unsigned short* __restrict__ A,
              const short* __restrict__ WT, const float* __restrict__ bias,
              float* __restrict__ Y, unsigned short* __restrict__ Yb,
              int ldY, int rows, int K)
{
    __shared__ short Alds[128][32];
    __shared__ short Wlds[128][32];

    const int t    = threadIdx.x;
    const int lane = t & 63;
    const int w    = t >> 6;
    const int r0   = blockIdx.x * 128;
    const int c0   = blockIdx.y * 128;
    const short* WTb = WT + (size_t)c0 * K;

    f32x4 acc[4][4];
#pragma unroll
    for (int m = 0; m < 4; ++m)
#pragma unroll
        for (int n = 0; n < 4; ++n) acc[m][n] = (f32x4)0.f;

    const int srow = t >> 1;          // 0..127
    const int skk  = (t & 1) * 16;    // 0 or 16 shorts
    const int wn   = t >> 1;
    const int wkp  = (t & 1) * 16;

    const int wr   = (w >> 1) * 64;
    const int wc   = (w & 1) * 64;
    const int rsel = lane & 15;
    const int kb   = (lane >> 4) * 8;

    for (int k0 = 0; k0 < K; k0 += 32) {
        {
            int rg = r0 + srow; rg = rg < rows ? rg : rows - 1;
            const unsigned short* p = A + (size_t)rg * K + (k0 + skk);
            s16x8 a0 = *(const s16x8*)p;
            s16x8 a1 = *(const s16x8*)(p + 8);
            int sw = ((srow >> 1) & 3) * 8;
            *(s16x8*)&Alds[srow][skk ^ sw]       = a0;
            *(s16x8*)&Alds[srow][(skk + 8) ^ sw] = a1;
        }
        {
            const short* p = WTb + (size_t)wn * K + (k0 + wkp);
            s16x8 w0 = *(const s16x8*)p;
            s16x8 w1 = *(const s16x8*)(p + 8);
            int sw = ((wn >> 1) & 3) * 8;
            *(s16x8*)&Wlds[wn][wkp ^ sw]       = w0;
            *(s16x8*)&Wlds[wn][(wkp + 8) ^ sw] = w1;
        }
        __syncthreads();

        s16x8 af[4], bfr[4];
#pragma unroll
        for (int m = 0; m < 4; ++m) {
            int r = wr + m * 16 + rsel;
            af[m] = *(const s16x8*)&Alds[r][kb ^ (((r >> 1) & 3) * 8)];
        }
#pragma unroll
        for (int n = 0; n < 4; ++n) {
            int r = wc + n * 16 + rsel;
            bfr[n] = *(const s16x8*)&Wlds[r][kb ^ (((r >> 1) & 3) * 8)];
        }
#pragma unroll
        for (int m = 0; m < 4; ++m)
#pragma unroll
            for (int n = 0; n < 4; ++n)
                acc[m][n] = __builtin_amdgcn_mfma_f32_16x16x32_bf16(
                    __builtin_bit_cast(bf16x8, af[m]),
                    __builtin_bit_cast(bf16x8, bfr[n]), acc[m][n], 0, 0, 0);
        __syncthreads();
    }

    const int crow = (lane >> 4) * 4;
#pragma unroll
    for (int m = 0; m < 4; ++m) {
        int rbase = r0 + wr + m * 16 + crow;
#pragma unroll
        for (int i = 0; i < 4; ++i) {
            int gr = rbase + i;
            bool ok = (gr < rows);
#pragma unroll
            for (int n = 0; n < 4; ++n) {
                int cc = c0 + wc + n * 16 + rsel;
                float v = acc[m][n][i];
                if (bias) v += bias[cc];
                if (ok) {
                    if (OUTBF) Yb[(size_t)gr * ldY + cc] = (unsigned short)f2b(v);
                    else       Y [(size_t)gr * ldY + cc] = v;
                }
            }
        }
    }
}

// ---------------------------------------------------------------------------
// CSR build
// ---------------------------------------------------------------------------
__global__ __launch_bounds__(256)
void hist_rows(const int* __restrict__ row, int* __restrict__ cnt)
{
    int e = blockIdx.x * 256 + threadIdx.x;
    if (e < EE) atomicAdd(&cnt[row[e]], 1);
}

__global__ __launch_bounds__(1024)
void scan_a(const int* __restrict__ cnt, int* __restrict__ rp, int* __restrict__ bsum)
{
    __shared__ int tmp[1024];
    int t = threadIdx.x, g = blockIdx.x * 1024 + t;
    int v = (g < NN) ? cnt[g] : 0;
    tmp[t] = v;
    __syncthreads();
    for (int off = 1; off < 1024; off <<= 1) {
        int a = (t >= off) ? tmp[t - off] : 0;
        __syncthreads();
        tmp[t] += a;
        __syncthreads();
    }
    if (g < NN) rp[g] = tmp[t] - v;          // local exclusive
    if (t == 1023) bsum[blockIdx.x] = tmp[t];
}

__global__ __launch_bounds__(64)
void scan_b(int* __restrict__ bsum, int nb)
{
    int lane = threadIdx.x;
    int orig = (lane < nb) ? bsum[lane] : 0;
    int v = orig;
    for (int off = 1; off < 64; off <<= 1) {
        int u = __shfl_up(v, off);
        if (lane >= off) v += u;
    }
    if (lane < nb) bsum[lane] = v - orig;    // exclusive
}

__global__ __launch_bounds__(1024)
void scan_c(int* __restrict__ rp, int* __restrict__ cur, const int* __restrict__ bsum)
{
    int t = threadIdx.x, g = blockIdx.x * 1024 + t;
    if (g < NN) {
        int v = rp[g] + bsum[blockIdx.x];
        rp[g] = v; cur[g] = v;
    }
    if (g == 0) rp[NN] = EE;
}

__global__ __launch_bounds__(256)
void scatter_edges(const int* __restrict__ row, const int* __restrict__ col,
                   const float* __restrict__ val, int* __restrict__ cur,
                   int2* __restrict__ pedge)
{
    int e = blockIdx.x * 256 + threadIdx.x;
    if (e >= EE) return;
    int p = atomicAdd(&cur[row[e]], 1);
    pedge[p] = make_int2(col[e], __float_as_int(val[e]));
}

// ---------------------------------------------------------------------------
// CSR SpMM with bf16 gather source. f32 out (+ optional bf16 copy).
// ---------------------------------------------------------------------------
template<bool WRITEB>
__global__ __launch_bounds__(256)
void spmm_csr(const int* __restrict__ rp, const int2* __restrict__ pedge,
              const unsigned short* __restrict__ xb,
              float* __restrict__ y, unsigned short* __restrict__ yb)
{
    int w    = (blockIdx.x * 256 + threadIdx.x) >> 6;
    int lane = threadIdx.x & 63;
    if (w >= NN) return;
    int s = rp[w], e = rp[w + 1];
    int d = lane * 2;
    float ax = 0.f, ay = 0.f;
    int i = s;
    for (; i + 4 <= e; i += 4) {
        int2 e0 = pedge[i], e1 = pedge[i+1], e2 = pedge[i+2], e3 = pedge[i+3];
        unsigned x0 = *(const unsigned*)(xb + (size_t)e0.x * 128 + d);
        unsigned x1 = *(const unsigned*)(xb + (size_t)e1.x * 128 + d);
        unsigned x2 = *(const unsigned*)(xb + (size_t)e2.x * 128 + d);
        unsigned x3 = *(const unsigned*)(xb + (size_t)e3.x * 128 + d);
        float v0 = __builtin_bit_cast(float, e0.y);
        float v1 = __builtin_bit_cast(float, e1.y);
        float v2 = __builtin_bit_cast(float, e2.y);
        float v3 = __builtin_bit_cast(float, e3.y);
        ax += v0 * blo(x0) + v1 * blo(x1) + v2 * blo(x2) + v3 * blo(x3);
        ay += v0 * bhi(x0) + v1 * bhi(x1) + v2 * bhi(x2) + v3 * bhi(x3);
    }
    for (; i < e; ++i) {
        int2 e0 = pedge[i];
        unsigned x0 = *(const unsigned*)(xb + (size_t)e0.x * 128 + d);
        float v0 = __builtin_bit_cast(float, e0.y);
        ax += v0 * blo(x0); ay += v0 * bhi(x0);
    }
    f32x2 r; r.x = ax; r.y = ay;
    *(f32x2*)(y + (size_t)w * 128 + d) = r;
    if (WRITEB) *(unsigned*)(yb + (size_t)w * 128 + d) = pk2(ax, ay);
}

// ---------------------------------------------------------------------------
// BN stats / fold / gather-norm (bf16 out, fused 3 regions)
// ---------------------------------------------------------------------------
__global__ __launch_bounds__(256)
void colstats(const float* __restrict__ low, const float* __restrict__ mid,
              float* __restrict__ stats, int nrows)
{
    const float* src = blockIdx.y ? mid : low;
    int c = threadIdx.x & 127;
    int h = threadIdx.x >> 7;
    int rs = blockIdx.x * 512;
    int re = min(rs + 512, nrows);
    float s1 = 0.f, s2 = 0.f;
    for (int r = rs + h; r < re; r += 2) {
        float xv = src[(size_t)r * 128 + c];
        s1 += xv; s2 += xv * xv;
    }
    __shared__ float l1[256], l2[256];
    l1[threadIdx.x] = s1; l2[threadIdx.x] = s2;
    __syncthreads();
    if (h == 0) {
        s1 = l1[c] + l1[128 + c];
        s2 = l2[c] + l2[128 + c];
        atomicAdd(&stats[blockIdx.y * 256 + c],       s1);
        atomicAdd(&stats[blockIdx.y * 256 + 128 + c], s2);
    }
}

__global__ __launch_bounds__(256)
void bn_scalebias(const float* __restrict__ stats,
                  const float* g1, const float* b1,
                  const float* g2, const float* b2,
                  float* __restrict__ sb, float inv_n)
{
    int t = threadIdx.x;
    int mat = t >> 7, c = t & 127;
    float mean = stats[mat * 256 + c] * inv_n;
    float var  = stats[mat * 256 + 128 + c] * inv_n - mean * mean;
    float s = (mat ? g2[c] : g1[c]) * rsqrtf(var + 1e-5f);
    float tt = (mat ? b2[c] : b1[c]) - mean * s;
    sb[mat * 256 + c] = s;
    sb[mat * 256 + 128 + c] = tt;
}

__global__ __launch_bounds__(256)
void gather_norm(const float* __restrict__ low, const float* __restrict__ mid,
                 const float* __restrict__ sb, const int* __restrict__ ts,
                 unsigned short* __restrict__ out)
{
    int idx = blockIdx.x * 256 + threadIdx.x;   // grid 24576 -> r<24576
    int c   = idx & 127;
    int seq = (idx >> 7) & 1;
    int r   = idx >> 8;
    int node;
    if      (r < 4096) node = ts[r * 6];
    else if (r < 8192) node = ts[(r - 4096) * 6 + 1];
    else { int rr = r - 8192; node = ts[(rr >> 2) * 6 + 2 + (rr & 3)]; }
    float xv = (seq ? mid : low)[(size_t)node * 128 + c];
    float yv = xv * sb[seq * 256 + c] + sb[seq * 256 + 128 + c];
    out[(size_t)r * 256 + seq * 128 + c] = (unsigned short)f2b(yv);
}

// ---------------------------------------------------------------------------
// 2-token attention on bf16 qkv (rows stride 384: q|k|v). LAYER 1 decodes
// the 4 flows; LAYER 2 is uniform self-attn. One wave per batch element.
// ---------------------------------------------------------------------------
template<int LAYER>
__global__ __launch_bounds__(256)
void attn_fused(const unsigned short* __restrict__ qkv,
                unsigned short* __restrict__ h, int ntot)
{
    int gw   = (blockIdx.x * 256 + threadIdx.x) >> 6;
    int lane = threadIdx.x & 63;
    if (gw >= ntot) return;
    int qtok, ktok, orow;
    if (LAYER == 1) {
        if      (gw < 4096)  { int g = gw;         qtok = 8192  + g*2; ktok = g*2;          orow = g*2; }
        else if (gw < 8192)  { int g = gw - 4096;  qtok = g*2;         ktok = 8192 + g*2;   orow = 8192 + g*2; }
        else if (gw < 24576) { int g = gw - 8192;  qtok = 16384 + g*2; ktok = (g>>2)*2;     orow = 16384 + g*2; }
        else                 { int g = gw - 24576; qtok = (g>>2)*2;    ktok = 16384 + g*2;  orow = 49152 + g*2; }
    } else {
        qtok = gw * 2; ktok = gw * 2; orow = gw * 2;
    }
    int d = lane * 2;
    unsigned q0 = *(const unsigned*)(qkv + (size_t)qtok * 384 + d);
    unsigned q1 = *(const unsigned*)(qkv + (size_t)(qtok+1) * 384 + d);
    unsigned k0 = *(const unsigned*)(qkv + (size_t)ktok * 384 + 128 + d);
    unsigned k1 = *(const unsigned*)(qkv + (size_t)(ktok+1) * 384 + 128 + d);
    float s00 = blo(q0)*blo(k0) + bhi(q0)*bhi(k0);
    float s01 = blo(q0)*blo(k1) + bhi(q0)*bhi(k1);
    float s10 = blo(q1)*blo(k0) + bhi(q1)*bhi(k0);
    float s11 = blo(q1)*blo(k1) + bhi(q1)*bhi(k1);
#pragma unroll
    for (int off = 32; off; off >>= 1) {
        s00 += __shfl_xor(s00, off);
        s01 += __shfl_xor(s01, off);
        s10 += __shfl_xor(s10, off);
        s11 += __shfl_xor(s11, off);
    }
    const float scale = 0.08838834764831845f;   // 1/sqrt(128)
    s00 *= scale; s01 *= scale; s10 *= scale; s11 *= scale;
    // softmax over QUERY axis (per key column)
    float m0 = fmaxf(s00, s10), m1 = fmaxf(s01, s11);
    float e00 = __expf(s00 - m0), e10 = __expf(s10 - m0);
    float e01 = __expf(s01 - m1), e11 = __expf(s11 - m1);
    float i0 = 1.f / (e00 + e10), i1 = 1.f / (e01 + e11);
    float a00 = e00 * i0, a10 = e10 * i0;
    float a01 = e01 * i1, a11 = e11 * i1;
    unsigned v0 = *(const unsigned*)(qkv + (size_t)ktok * 384 + 256 + d);
    unsigned v1 = *(const unsigned*)(qkv + (size_t)(ktok+1) * 384 + 256 + d);
    float h0x = a00*blo(v0) + a01*blo(v1), h0y = a00*bhi(v0) + a01*bhi(v1);
    float h1x = a10*blo(v0) + a11*blo(v1), h1y = a10*bhi(v0) + a11*bhi(v1);
    *(unsigned*)(h + (size_t)orow * 128 + d)       = pk2(h0x, h0y);
    *(unsigned*)(h + (size_t)(orow + 1) * 128 + d) = pk2(h1x, h1y);
}

// ---------------------------------------------------------------------------
__global__ __launch_bounds__(256)
void scores_kernel(const float* __restrict__ cat, float* __restrict__ scores)
{
    int gw   = (blockIdx.x * 256 + threadIdx.x) >> 6;
    int lane = threadIdx.x & 63;
    if (gw >= 20480) return;
    const float *pa, *pb;
    if (gw < BQ) { pa = cat + (size_t)gw * 128;            pb = cat + (size_t)(BQ + gw) * 128; }
    else { int n = gw - BQ; pa = cat + (size_t)(2*BQ + n) * 128; pb = cat + (size_t)(2*BQ + BQ*NNEG + n) * 128; }
    f32x2 a = *(const f32x2*)(pa + lane * 2);
    f32x2 b = *(const f32x2*)(pb + lane * 2);
    float s = a.x * b.x + a.y * b.y;
#pragma unroll
    for (int off = 32; off; off >>= 1) s += __shfl_xor(s, off);
    if (lane == 0) scores[gw] = s;
}

__global__ __launch_bounds__(256)
void loss_kernel(const float* __restrict__ scores, float* __restrict__ out)
{
    int t = threadIdx.x;
    float acc = 0.f;
    for (int i = t; i < BQ * NNEG; i += 256) {
        int b = i >> 2;
        float x = scores[b] - scores[BQ + i];
        float sig = 1.f / (1.f + __expf(-x));
        acc += __logf(sig + 1e-9f);
    }
    __shared__ float red[256];
    red[t] = acc; __syncthreads();
    for (int s = 128; s > 0; s >>= 1) { if (t < s) red[t] += red[t + s]; __syncthreads(); }
    if (t == 0) out[0] = -red[0] / (float)(BQ * NNEG);
}

// ---------------------------------------------------------------------------
// Weight packing: pack_wc (big) + pack_misc (everything else)
// ---------------------------------------------------------------------------
__global__ void pack_wc(const float* __restrict__ W2, const float* __restrict__ W3,
                        const float* __restrict__ We, short* __restrict__ WcT)
{
    int k = blockIdx.x, n = threadIdx.x;
    const float* Wrow = (k < 768) ? (W2 + (size_t)k * 128) : (W3 + (size_t)(k - 768) * 128);
    const float* Web  = We + ((k < 768) ? 0 : 128 * 128);
    float acc = 0.f;
    for (int j = 0; j < 128; ++j) acc += Wrow[j] * Web[j * 128 + n];
    WcT[(size_t)n * 1536 + k] = f2b(acc);
}

__global__ __launch_bounds__(128)
void pack_misc(const float* PT, const float* We,
               const float* b2, const float* b3, const float* bemb,
               const float* Wq1, const float* Wk1, const float* Wv1,
               const float* bq1, const float* bk1, const float* bv1,
               const float* Wq2, const float* Wk2, const float* Wv2,
               const float* bq2, const float* bk2, const float* bv2,
               const float* Wlow, const float* Wmid, const float* Wct,
               float* ptab2, float* bias_c,
               short* Wqkv1T, float* bqkv1,
               short* Wqkv2T, float* bqkv2,
               short* WlowT, short* WmidT, short* WcatT)
{
    int b = blockIdx.x, t = threadIdx.x;
    if (b < 100) {
        const float* Web = We + 256 * 128;
        float acc = 0.f;
        for (int j = 0; j < 128; ++j) acc += PT[b * 128 + j] * Web[j * 128 + t];
        ptab2[b * 128 + t] = acc;
    } else if (b == 100) {
        float acc = bemb[t];
        for (int j = 0; j < 128; ++j)
            acc += b2[j] * We[j * 128 + t] + b3[j] * We[(128 + j) * 128 + t];
        bias_c[t] = acc;
    } else if (b < 229) {
        int k = b - 101;
        Wqkv1T[(size_t)(      t) * 128 + k] = f2b(Wq1[k * 128 + t]);
        Wqkv1T[(size_t)(128 + t) * 128 + k] = f2b(Wk1[k * 128 + t]);
        Wqkv1T[(size_t)(256 + t) * 128 + k] = f2b(Wv1[k * 128 + t]);
        if (k == 0) { bqkv1[t] = bq1[t]; bqkv1[128 + t] = bk1[t]; bqkv1[256 + t] = bv1[t]; }
    } else if (b < 357) {
        int k = b - 229;
        Wqkv2T[(size_t)(      t) * 128 + k] = f2b(Wq2[k * 128 + t]);
        Wqkv2T[(size_t)(128 + t) * 128 + k] = f2b(Wk2[k * 128 + t]);
        Wqkv2T[(size_t)(256 + t) * 128 + k] = f2b(Wv2[k * 128 + t]);
        if (k == 0) { bqkv2[t] = bq2[t]; bqkv2[128 + t] = bk2[t]; bqkv2[256 + t] = bv2[t]; }
    } else if (b < 485) {
        int k = b - 357;
        WlowT[(size_t)t * 128 + k] = f2b(Wlow[k * 128 + t]);
    } else if (b < 613) {
        int k = b - 485;
        WmidT[(size_t)t * 128 + k] = f2b(Wmid[k * 128 + t]);
    } else {
        int k = b - 613;   // 0..255
        WcatT[(size_t)t * 256 + k] = f2b(Wct[k * 128 + t]);
    }
}

// ---------------------------------------------------------------------------
extern "C" void kernel_launch(void* const* d_in, const int* in_sizes, int n_in,
                              void* d_out, int out_size, void* d_ws, size_t ws_size,
                              hipStream_t stream)
{
    const float* features = (const float*)d_in[0];
    const int*   price    = (const int*)  d_in[1];
    const int*   adj_row  = (const int*)  d_in[2];
    const int*   adj_col  = (const int*)  d_in[3];
    const float* adj_val  = (const float*)d_in[4];
    const int*   train_set= (const int*)  d_in[5];
    const float* W_cid2   = (const float*)d_in[6];
    const float* b_cid2   = (const float*)d_in[7];
    const float* W_cid3   = (const float*)d_in[8];
    const float* b_cid3   = (const float*)d_in[9];
    const float* ptable   = (const float*)d_in[10];
    const float* W_emb    = (const float*)d_in[11];
    const float* b_emb    = (const float*)d_in[12];
    const float* W_low    = (const float*)d_in[13];
    const float* W_mid    = (const float*)d_in[14];
    const float* bn1_g    = (const float*)d_in[15];
    const float* bn1_b    = (const float*)d_in[16];
    const float* bn2_g    = (const float*)d_in[17];
    const float* bn2_b    = (const float*)d_in[18];
    const float* Wq1 = (const float*)d_in[19]; const float* bq1 = (const float*)d_in[20];
    const float* Wk1 = (const float*)d_in[21]; const float* bk1 = (const float*)d_in[22];
    const float* Wv1 = (const float*)d_in[23]; const float* bv1 = (const float*)d_in[24];
    const float* Wq2 = (const float*)d_in[25]; const float* bq2 = (const float*)d_in[26];
    const float* Wk2 = (const float*)d_in[27]; const float* bk2 = (const float*)d_in[28];
    const float* Wv2 = (const float*)d_in[29]; const float* bv2 = (const float*)d_in[30];
    const float* Wcat= (const float*)d_in[31]; const float* bcat= (const float*)d_in[32];

    float* ws = (float*)d_ws;

    // ---- workspace layout (float offsets, all regions 16B-aligned) ----
    const size_t SZ_NODE = (size_t)NN * 128;                 // 6,400,000
    float*          item    = ws;                            // f32
    float*          ag      = ws + 6400000;
    float*          ag2     = ws + 12800000;
    float*          low     = ws + 19200000;
    float*          mid     = ws + 25600000;
    unsigned short* item_bf = (unsigned short*)(ws + 32000000);   // 6.4M sh
    unsigned short* ag_bf   = (unsigned short*)(ws + 35200000);
    unsigned short* gath_b  = (unsigned short*)(ws + 38400000);   // 49152*128 sh
    unsigned short* qkv1b   = (unsigned short*)(ws + 41545728);   // 49152*384 sh
    unsigned short* h1b     = (unsigned short*)(ws + 50982912);   // 81920*128 sh
    unsigned short* qkv2b   = (unsigned short*)(ws + 56225792);   // 81920*384 sh
    unsigned short* h2b     = (unsigned short*)(ws + 71954432);   // 81920*128 sh
    float*          cat     = ws + 77197312;                      // 40960*128 f32
    int*            ibase   = (int*)(ws + 82440192);
    int*   rp    = ibase;                    // 50016
    int*   cur   = ibase + 50016;            // 50016
    float* stats = (float*)(ibase + 100032); // 512   (memset together with cur)
    int*   bsum  = ibase + 100544;           // 64
    int2*  pedge = (int2*)(ibase + 100640);  // 1,600,000 int2
    float* wb    = (float*)(ibase + 3300640);
    short* WcT    = (short*)wb;              // 98304 f
    float* ptab2  = wb + 98304;              // 12800
    float* bias_c = wb + 111104;             // 128
    short* Wqkv1T = (short*)(wb + 111232);   // 24576 f
    float* bqkv1  = wb + 135808;             // 384
    short* Wqkv2T = (short*)(wb + 136192);   // 24576 f
    float* bqkv2  = wb + 160768;             // 384
    short* WlowT  = (short*)(wb + 161152);   // 8192 f
    short* WmidT  = (short*)(wb + 169344);   // 8192 f
    short* WcatT  = (short*)(wb + 177536);   // 16384 f
    float* sb     = wb + 193920;             // 512
    float* scores = wb + 194432;             // 20480

    // ---- weight packing ----
    hipLaunchKernelGGL(pack_wc,   dim3(1536), dim3(128), 0, stream, W_cid2, W_cid3, W_emb, WcT);
    hipLaunchKernelGGL(pack_misc, dim3(869),  dim3(128), 0, stream,
                       ptable, W_emb, b_cid2, b_cid3, b_emb,
                       Wq1, Wk1, Wv1, bq1, bk1, bv1,
                       Wq2, Wk2, Wv2, bq2, bk2, bv2,
                       W_low, W_mid, Wcat,
                       ptab2, bias_c, Wqkv1T, bqkv1, Wqkv2T, bqkv2,
                       WlowT, WmidT, WcatT);

    // one memset covers cur (50016 ints) + stats (512 floats), contiguous
    hipMemsetAsync(cur, 0, (50016 + 512) * 4, stream);

    // ---- CSR build ----
    hipLaunchKernelGGL(hist_rows,     dim3(6250), dim3(256),  0, stream, adj_row, cur);
    hipLaunchKernelGGL(scan_a,        dim3(49),   dim3(1024), 0, stream, cur, rp, bsum);
    hipLaunchKernelGGL(scan_b,        dim3(1),    dim3(64),   0, stream, bsum, 49);
    hipLaunchKernelGGL(scan_c,        dim3(49),   dim3(1024), 0, stream, rp, cur, bsum);
    hipLaunchKernelGGL(scatter_edges, dim3(6250), dim3(256),  0, stream,
                       adj_row, adj_col, adj_val, cur, pedge);

    // ---- item = relu(features @ Wc + ptab2[price] + bias_c)  (f32 + bf16) ----
    hipLaunchKernelGGL((gemm_bf16<false, true, true, true>), dim3(391, 1), dim3(256), 0, stream,
                       features, nullptr, 1.f, 0.f, WcT, bias_c, price, ptab2,
                       item, item_bf, 128, NN, 1536);

    // ---- ag = A @ item ; low = (0.5ag + 0.5item) @ W_low ----
    hipLaunchKernelGGL((spmm_csr<true>), dim3(12500), dim3(256), 0, stream,
                       rp, pedge, item_bf, ag, ag_bf);
    hipLaunchKernelGGL((gemm_bf16<true, false, false, false>), dim3(391, 1), dim3(256), 0, stream,
                       ag, item, 0.5f, 0.5f, WlowT, nullptr, nullptr, nullptr,
                       low, nullptr, 128, NN, 128);

    // ---- ag2 = A @ ag ; mid = (0.5ag2 - 0.5item) @ W_mid ----
    hipLaunchKernelGGL((spmm_csr<false>), dim3(12500), dim3(256), 0, stream,
                       rp, pedge, ag_bf, ag2, nullptr);
    hipLaunchKernelGGL((gemm_bf16<true, false, false, false>), dim3(391, 1), dim3(256), 0, stream,
                       ag2, item, 0.5f, -0.5f, WmidT, nullptr, nullptr, nullptr,
                       mid, nullptr, 128, NN, 128);

    // ---- BN stats + fold ----
    hipLaunchKernelGGL(colstats, dim3(98, 2), dim3(256), 0, stream, low, mid, stats, NN);
    hipLaunchKernelGGL(bn_scalebias, dim3(1), dim3(256), 0, stream,
                       stats, bn1_g, bn1_b, bn2_g, bn2_b, sb, 1.f / (float)NN);

    // ---- gather + normalize -> bf16 (key | pos | neg fused) ----
    hipLaunchKernelGGL(gather_norm, dim3(24576), dim3(256), 0, stream,
                       low, mid, sb, train_set, gath_b);

    // ---- layer-1 qkv (bf16 in, bf16 out) ----
    hipLaunchKernelGGL((gemm_a16<true>), dim3(384, 3), dim3(256), 0, stream,
                       gath_b, Wqkv1T, bqkv1, nullptr, qkv1b, 384, 49152, 128);

    // ---- layer-1 attention (4 flows fused) ----
    hipLaunchKernelGGL((attn_fused<1>), dim3(10240), dim3(256), 0, stream, qkv1b, h1b, 40960);

    // ---- layer-2 qkv ----
    hipLaunchKernelGGL((gemm_a16<true>), dim3(640, 3), dim3(256), 0, stream,
                       h1b, Wqkv2T, bqkv2, nullptr, qkv2b, 384, 81920, 128);

    // ---- layer-2 attention (uniform self-attn) ----
    hipLaunchKernelGGL((attn_fused<2>), dim3(10240), dim3(256), 0, stream, qkv2b, h2b, 40960);

    // ---- cat GEMM (bf16 in, f32 out) ----
    hipLaunchKernelGGL((gemm_a16<false>), dim3(320, 1), dim3(256), 0, stream,
                       h2b, WcatT, bcat, cat, nullptr, 128, 40960, 256);

    // ---- scores + loss ----
    hipLaunchKernelGGL(scores_kernel, dim3(5120), dim3(256), 0, stream, cat, scores);
    hipLaunchKernelGGL(loss_kernel, dim3(1), dim3(256), 0, stream, scores, (float*)d_out);
}

// Round 10
// 1046.584 us; speedup vs baseline: 3.3632x; 1.0728x over previous
//
#include <hip/hip_runtime.h>
#include <hip/hip_bf16.h>

// ---------------------------------------------------------------------------
// SComGNN r7: bf16-only node pipeline.
// item GEMM(bf16 out) -> CSR build -> spmm x2 (bf16 in/out) ->
// fused low/mid GEMM (K-concat bf16, +-0.5 folded into weights) ->
// BN(bf16 stats) -> gather-norm(bf16) -> qkv/attn chain (bf16) -> cat -> loss
// ---------------------------------------------------------------------------

typedef __attribute__((ext_vector_type(4))) float  f32x4;
typedef __attribute__((ext_vector_type(2))) float  f32x2;
typedef __attribute__((ext_vector_type(8))) short  s16x8;
typedef __attribute__((ext_vector_type(4))) short  s16x4;
typedef __attribute__((ext_vector_type(8))) __bf16 bf16x8;

#define NN   50000
#define EE   1600000
#define BQ   4096
#define NNEG 4

__device__ __forceinline__ short f2b(float x) {
    union { float f; unsigned u; } c; c.f = x;
    unsigned r = c.u + 0x7FFF + ((c.u >> 16) & 1);   // RNE to bf16
    return (short)(r >> 16);
}
__device__ __forceinline__ float blo(unsigned u) { return __builtin_bit_cast(float, u << 16); }
__device__ __forceinline__ float bhi(unsigned u) { return __builtin_bit_cast(float, u & 0xffff0000u); }
__device__ __forceinline__ unsigned pk2(float a, float b) {
    return (unsigned)(unsigned short)f2b(a) | ((unsigned)(unsigned short)f2b(b) << 16);
}

// ---------------------------------------------------------------------------
// Item GEMM: f32 A (features), K=1536, epilogue bias+price+relu, bf16 out.
// ---------------------------------------------------------------------------
__global__ __launch_bounds__(256)
void gemm_item(const float* __restrict__ A1,
               const short* __restrict__ WT, const float* __restrict__ bias,
               const int* __restrict__ price, const float* __restrict__ ptab,
               unsigned short* __restrict__ Yb, int rows, int K)
{
    __shared__ short Alds[128][32];
    __shared__ short Wlds[128][32];

    const int t    = threadIdx.x;
    const int lane = t & 63;
    const int w    = t >> 6;
    const int r0   = blockIdx.x * 128;

    f32x4 acc[4][4];
#pragma unroll
    for (int m = 0; m < 4; ++m)
#pragma unroll
        for (int n = 0; n < 4; ++n) acc[m][n] = (f32x4)0.f;

    const int srow = t >> 3;
    const int skk  = (t & 7) * 4;
    const int wn   = t >> 1;
    const int wkp  = (t & 1) * 16;

    const int wr   = (w >> 1) * 64;
    const int wc   = (w & 1) * 64;
    const int rsel = lane & 15;
    const int kb   = (lane >> 4) * 8;

    for (int k0 = 0; k0 < K; k0 += 32) {
#pragma unroll
        for (int i = 0; i < 4; ++i) {
            int r  = srow + i * 32;
            int rg = r0 + r; rg = rg < rows ? rg : rows - 1;
            float4 va = *(const float4*)(A1 + (size_t)rg * K + (k0 + skk));
            s16x4 sv; sv[0]=f2b(va.x); sv[1]=f2b(va.y); sv[2]=f2b(va.z); sv[3]=f2b(va.w);
            int sw = ((r >> 1) & 3) * 8;
            *(s16x4*)&Alds[r][skk ^ sw] = sv;
        }
        {
            const short* p = WT + (size_t)wn * K + (k0 + wkp);
            s16x8 w0 = *(const s16x8*)p;
            s16x8 w1 = *(const s16x8*)(p + 8);
            int sw = ((wn >> 1) & 3) * 8;
            *(s16x8*)&Wlds[wn][wkp ^ sw]       = w0;
            *(s16x8*)&Wlds[wn][(wkp + 8) ^ sw] = w1;
        }
        __syncthreads();

        s16x8 af[4], bfr[4];
#pragma unroll
        for (int m = 0; m < 4; ++m) {
            int r = wr + m * 16 + rsel;
            af[m] = *(const s16x8*)&Alds[r][kb ^ (((r >> 1) & 3) * 8)];
        }
#pragma unroll
        for (int n = 0; n < 4; ++n) {
            int r = wc + n * 16 + rsel;
            bfr[n] = *(const s16x8*)&Wlds[r][kb ^ (((r >> 1) & 3) * 8)];
        }
#pragma unroll
        for (int m = 0; m < 4; ++m)
#pragma unroll
            for (int n = 0; n < 4; ++n)
                acc[m][n] = __builtin_amdgcn_mfma_f32_16x16x32_bf16(
                    __builtin_bit_cast(bf16x8, af[m]),
                    __builtin_bit_cast(bf16x8, bfr[n]), acc[m][n], 0, 0, 0);
        __syncthreads();
    }

    const int crow = (lane >> 4) * 4;
#pragma unroll
    for (int m = 0; m < 4; ++m) {
        int rbase = r0 + wr + m * 16 + crow;
#pragma unroll
        for (int i = 0; i < 4; ++i) {
            int gr = rbase + i;
            bool ok = (gr < rows);
            int pidx = ok ? price[gr] : 0;
#pragma unroll
            for (int n = 0; n < 4; ++n) {
                int cc = wc + n * 16 + rsel;
                float v = acc[m][n][i] + bias[cc] + ptab[pidx * 128 + cc];
                v = fmaxf(v, 0.f);
                if (ok) Yb[(size_t)gr * 128 + cc] = (unsigned short)f2b(v);
            }
        }
    }
}

// ---------------------------------------------------------------------------
// Fused low/mid GEMM. Logical A = [tabA | item] (K=256, bf16 tables, row
// stride 128); W pre-packed [128][256] with +-0.5 folded. bf16 out, no bias.
// blockIdx.y: 0 = low (ag), 1 = mid (ag2).
// ---------------------------------------------------------------------------
__global__ __launch_bounds__(256)
void gemm_lowmid(const unsigned short* __restrict__ ag_bf,
                 const unsigned short* __restrict__ ag2_bf,
                 const unsigned short* __restrict__ item_bf,
                 const short* __restrict__ WlowT2, const short* __restrict__ WmidT2,
                 unsigned short* __restrict__ low_bf, unsigned short* __restrict__ mid_bf,
                 int rows)
{
    __shared__ short Alds[128][32];
    __shared__ short Wlds[128][32];

    const unsigned short* A0 = blockIdx.y ? ag2_bf : ag_bf;
    const short*          WT = blockIdx.y ? WmidT2 : WlowT2;
    unsigned short*       Yb = blockIdx.y ? mid_bf : low_bf;

    const int t    = threadIdx.x;
    const int lane = t & 63;
    const int w    = t >> 6;
    const int r0   = blockIdx.x * 128;

    f32x4 acc[4][4];
#pragma unroll
    for (int m = 0; m < 4; ++m)
#pragma unroll
        for (int n = 0; n < 4; ++n) acc[m][n] = (f32x4)0.f;

    const int srow = t >> 1;          // 0..127
    const int skk  = (t & 1) * 16;
    const int wn   = t >> 1;
    const int wkp  = (t & 1) * 16;

    const int wr   = (w >> 1) * 64;
    const int wc   = (w & 1) * 64;
    const int rsel = lane & 15;
    const int kb   = (lane >> 4) * 8;

    for (int k0 = 0; k0 < 256; k0 += 32) {
        {
            int rg = r0 + srow; rg = rg < rows ? rg : rows - 1;
            const unsigned short* tab = (k0 < 128) ? A0 : item_bf;
            int kc = (k0 + skk) & 127;
            const unsigned short* p = tab + (size_t)rg * 128 + kc;
            s16x8 a0 = *(const s16x8*)p;
            s16x8 a1 = *(const s16x8*)(p + 8);
            int sw = ((srow >> 1) & 3) * 8;
            *(s16x8*)&Alds[srow][skk ^ sw]       = a0;
            *(s16x8*)&Alds[srow][(skk + 8) ^ sw] = a1;
        }
        {
            const short* p = WT + (size_t)wn * 256 + (k0 + wkp);
            s16x8 w0 = *(const s16x8*)p;
            s16x8 w1 = *(const s16x8*)(p + 8);
            int sw = ((wn >> 1) & 3) * 8;
            *(s16x8*)&Wlds[wn][wkp ^ sw]       = w0;
            *(s16x8*)&Wlds[wn][(wkp + 8) ^ sw] = w1;
        }
        __syncthreads();

        s16x8 af[4], bfr[4];
#pragma unroll
        for (int m = 0; m < 4; ++m) {
            int r = wr + m * 16 + rsel;
            af[m] = *(const s16x8*)&Alds[r][kb ^ (((r >> 1) & 3) * 8)];
        }
#pragma unroll
        for (int n = 0; n < 4; ++n) {
            int r = wc + n * 16 + rsel;
            bfr[n] = *(const s16x8*)&Wlds[r][kb ^ (((r >> 1) & 3) * 8)];
        }
#pragma unroll
        for (int m = 0; m < 4; ++m)
#pragma unroll
            for (int n = 0; n < 4; ++n)
                acc[m][n] = __builtin_amdgcn_mfma_f32_16x16x32_bf16(
                    __builtin_bit_cast(bf16x8, af[m]),
                    __builtin_bit_cast(bf16x8, bfr[n]), acc[m][n], 0, 0, 0);
        __syncthreads();
    }

    const int crow = (lane >> 4) * 4;
#pragma unroll
    for (int m = 0; m < 4; ++m) {
        int rbase = r0 + wr + m * 16 + crow;
#pragma unroll
        for (int i = 0; i < 4; ++i) {
            int gr = rbase + i;
            if (gr >= rows) continue;
#pragma unroll
            for (int n = 0; n < 4; ++n) {
                int cc = wc + n * 16 + rsel;
                Yb[(size_t)gr * 128 + cc] = (unsigned short)f2b(acc[m][n][i]);
            }
        }
    }
}

// ---------------------------------------------------------------------------
// bf16-A MFMA GEMM (qkv / cat). OUTBF selects output fmt.
// ---------------------------------------------------------------------------
template<bool OUTBF>
__global__ __launch_bounds__(256)
void gemm_a16(const unsigned short* __restrict__ A,
              const short* __restrict__ WT, const float* __restrict__ bias,
              float* __restrict__ Y, unsigned short* __restrict__ Yb,
              int ldY, int rows, int K)
{
    __shared__ short Alds[128][32];
    __shared__ short Wlds[128][32];

    const int t    = threadIdx.x;
    const int lane = t & 63;
    const int w    = t >> 6;
    const int r0   = blockIdx.x * 128;
    const int c0   = blockIdx.y * 128;
    const short* WTb = WT + (size_t)c0 * K;

    f32x4 acc[4][4];
#pragma unroll
    for (int m = 0; m < 4; ++m)
#pragma unroll
        for (int n = 0; n < 4; ++n) acc[m][n] = (f32x4)0.f;

    const int srow = t >> 1;
    const int skk  = (t & 1) * 16;
    const int wn   = t >> 1;
    const int wkp  = (t & 1) * 16;

    const int wr   = (w >> 1) * 64;
    const int wc   = (w & 1) * 64;
    const int rsel = lane & 15;
    const int kb   = (lane >> 4) * 8;

    for (int k0 = 0; k0 < K; k0 += 32) {
        {
            int rg = r0 + srow; rg = rg < rows ? rg : rows - 1;
            const unsigned short* p = A + (size_t)rg * K + (k0 + skk);
            s16x8 a0 = *(const s16x8*)p;
            s16x8 a1 = *(const s16x8*)(p + 8);
            int sw = ((srow >> 1) & 3) * 8;
            *(s16x8*)&Alds[srow][skk ^ sw]       = a0;
            *(s16x8*)&Alds[srow][(skk + 8) ^ sw] = a1;
        }
        {
            const short* p = WTb + (size_t)wn * K + (k0 + wkp);
            s16x8 w0 = *(const s16x8*)p;
            s16x8 w1 = *(const s16x8*)(p + 8);
            int sw = ((wn >> 1) & 3) * 8;
            *(s16x8*)&Wlds[wn][wkp ^ sw]       = w0;
            *(s16x8*)&Wlds[wn][(wkp + 8) ^ sw] = w1;
        }
        __syncthreads();

        s16x8 af[4], bfr[4];
#pragma unroll
        for (int m = 0; m < 4; ++m) {
            int r = wr + m * 16 + rsel;
            af[m] = *(const s16x8*)&Alds[r][kb ^ (((r >> 1) & 3) * 8)];
        }
#pragma unroll
        for (int n = 0; n < 4; ++n) {
            int r = wc + n * 16 + rsel;
            bfr[n] = *(const s16x8*)&Wlds[r][kb ^ (((r >> 1) & 3) * 8)];
        }
#pragma unroll
        for (int m = 0; m < 4; ++m)
#pragma unroll
            for (int n = 0; n < 4; ++n)
                acc[m][n] = __builtin_amdgcn_mfma_f32_16x16x32_bf16(
                    __builtin_bit_cast(bf16x8, af[m]),
                    __builtin_bit_cast(bf16x8, bfr[n]), acc[m][n], 0, 0, 0);
        __syncthreads();
    }

    const int crow = (lane >> 4) * 4;
#pragma unroll
    for (int m = 0; m < 4; ++m) {
        int rbase = r0 + wr + m * 16 + crow;
#pragma unroll
        for (int i = 0; i < 4; ++i) {
            int gr = rbase + i;
            bool ok = (gr < rows);
#pragma unroll
            for (int n = 0; n < 4; ++n) {
                int cc = c0 + wc + n * 16 + rsel;
                float v = acc[m][n][i];
                if (bias) v += bias[cc];
                if (ok) {
                    if (OUTBF) Yb[(size_t)gr * ldY + cc] = (unsigned short)f2b(v);
                    else       Y [(size_t)gr * ldY + cc] = v;
                }
            }
        }
    }
}

// ---------------------------------------------------------------------------
// CSR build
// ---------------------------------------------------------------------------
__global__ __launch_bounds__(256)
void hist_rows(const int* __restrict__ row, int* __restrict__ cnt)
{
    int e = blockIdx.x * 256 + threadIdx.x;
    if (e < EE) atomicAdd(&cnt[row[e]], 1);
}

__global__ __launch_bounds__(1024)
void scan_a(const int* __restrict__ cnt, int* __restrict__ rp, int* __restrict__ bsum)
{
    __shared__ int tmp[1024];
    int t = threadIdx.x, g = blockIdx.x * 1024 + t;
    int v = (g < NN) ? cnt[g] : 0;
    tmp[t] = v;
    __syncthreads();
    for (int off = 1; off < 1024; off <<= 1) {
        int a = (t >= off) ? tmp[t - off] : 0;
        __syncthreads();
        tmp[t] += a;
        __syncthreads();
    }
    if (g < NN) rp[g] = tmp[t] - v;          // local exclusive
    if (t == 1023) bsum[blockIdx.x] = tmp[t];
}

__global__ __launch_bounds__(64)
void scan_b(int* __restrict__ bsum, int nb)
{
    int lane = threadIdx.x;
    int orig = (lane < nb) ? bsum[lane] : 0;
    int v = orig;
    for (int off = 1; off < 64; off <<= 1) {
        int u = __shfl_up(v, off);
        if (lane >= off) v += u;
    }
    if (lane < nb) bsum[lane] = v - orig;    // exclusive
}

__global__ __launch_bounds__(1024)
void scan_c(int* __restrict__ rp, int* __restrict__ cur, const int* __restrict__ bsum)
{
    int t = threadIdx.x, g = blockIdx.x * 1024 + t;
    if (g < NN) {
        int v = rp[g] + bsum[blockIdx.x];
        rp[g] = v; cur[g] = v;
    }
    if (g == 0) rp[NN] = EE;
}

__global__ __launch_bounds__(256)
void scatter_edges(const int* __restrict__ row, const int* __restrict__ col,
                   const float* __restrict__ val, int* __restrict__ cur,
                   int2* __restrict__ pedge)
{
    int e = blockIdx.x * 256 + threadIdx.x;
    if (e >= EE) return;
    int p = atomicAdd(&cur[row[e]], 1);
    pedge[p] = make_int2(col[e], __float_as_int(val[e]));
}

// ---------------------------------------------------------------------------
// CSR SpMM: bf16 gather, f32 accumulate, bf16 store. 8-edge unroll for MLP.
// ---------------------------------------------------------------------------
__global__ __launch_bounds__(256)
void spmm_csr(const int* __restrict__ rp, const int2* __restrict__ pedge,
              const unsigned short* __restrict__ xb,
              unsigned short* __restrict__ yb)
{
    int w    = (blockIdx.x * 256 + threadIdx.x) >> 6;
    int lane = threadIdx.x & 63;
    if (w >= NN) return;
    int s = rp[w], e = rp[w + 1];
    int d = lane * 2;
    float ax = 0.f, ay = 0.f;
    int i = s;
    for (; i + 8 <= e; i += 8) {
        int2 ed[8]; unsigned xv[8];
#pragma unroll
        for (int j = 0; j < 8; ++j) ed[j] = pedge[i + j];
#pragma unroll
        for (int j = 0; j < 8; ++j)
            xv[j] = *(const unsigned*)(xb + (size_t)ed[j].x * 128 + d);
#pragma unroll
        for (int j = 0; j < 8; ++j) {
            float v = __builtin_bit_cast(float, ed[j].y);
            ax += v * blo(xv[j]);
            ay += v * bhi(xv[j]);
        }
    }
    for (; i < e; ++i) {
        int2 e0 = pedge[i];
        unsigned x0 = *(const unsigned*)(xb + (size_t)e0.x * 128 + d);
        float v0 = __builtin_bit_cast(float, e0.y);
        ax += v0 * blo(x0); ay += v0 * bhi(x0);
    }
    *(unsigned*)(yb + (size_t)w * 128 + d) = pk2(ax, ay);
}

// ---------------------------------------------------------------------------
// BN stats over bf16 low/mid: thread = (colpair, rowgroup)
// ---------------------------------------------------------------------------
__global__ __launch_bounds__(256)
void colstats(const unsigned short* __restrict__ low,
              const unsigned short* __restrict__ mid,
              float* __restrict__ stats, int nrows)
{
    const unsigned* src = (const unsigned*)(blockIdx.y ? mid : low);
    int p = threadIdx.x & 63;       // colpair 0..63
    int h = threadIdx.x >> 6;       // rowgroup 0..3
    int rs = blockIdx.x * 512;
    int re = min(rs + 512, nrows);
    float s1a = 0.f, s2a = 0.f, s1b = 0.f, s2b = 0.f;
    for (int r = rs + h; r < re; r += 4) {
        unsigned u = src[(size_t)r * 64 + p];
        float a = blo(u), b = bhi(u);
        s1a += a; s2a += a * a;
        s1b += b; s2b += b * b;
    }
    __shared__ float4 red[256];
    red[threadIdx.x] = make_float4(s1a, s2a, s1b, s2b);
    __syncthreads();
    if (h == 0) {
        float4 v0 = red[p], v1 = red[64 + p], v2 = red[128 + p], v3 = red[192 + p];
        float t1a = v0.x + v1.x + v2.x + v3.x;
        float t2a = v0.y + v1.y + v2.y + v3.y;
        float t1b = v0.z + v1.z + v2.z + v3.z;
        float t2b = v0.w + v1.w + v2.w + v3.w;
        int base = blockIdx.y * 256;
        atomicAdd(&stats[base + 2 * p],           t1a);
        atomicAdd(&stats[base + 2 * p + 1],       t1b);
        atomicAdd(&stats[base + 128 + 2 * p],     t2a);
        atomicAdd(&stats[base + 128 + 2 * p + 1], t2b);
    }
}

__global__ __launch_bounds__(256)
void bn_scalebias(const float* __restrict__ stats,
                  const float* g1, const float* b1,
                  const float* g2, const float* b2,
                  float* __restrict__ sb, float inv_n)
{
    int t = threadIdx.x;
    int mat = t >> 7, c = t & 127;
    float mean = stats[mat * 256 + c] * inv_n;
    float var  = stats[mat * 256 + 128 + c] * inv_n - mean * mean;
    float s = (mat ? g2[c] : g1[c]) * rsqrtf(var + 1e-5f);
    float tt = (mat ? b2[c] : b1[c]) - mean * s;
    sb[mat * 256 + c] = s;
    sb[mat * 256 + 128 + c] = tt;
}

// gather + normalize, bf16 in/out, u32 (2-col) granularity
__global__ __launch_bounds__(256)
void gather_norm(const unsigned short* __restrict__ low,
                 const unsigned short* __restrict__ mid,
                 const float* __restrict__ sb, const int* __restrict__ ts,
                 unsigned short* __restrict__ out)
{
    int idx = blockIdx.x * 256 + threadIdx.x;   // grid 12288 -> idx < 3,145,728
    int p   = idx & 63;
    int seq = (idx >> 6) & 1;
    int r   = idx >> 7;
    int node;
    if      (r < 4096) node = ts[r * 6];
    else if (r < 8192) node = ts[(r - 4096) * 6 + 1];
    else { int rr = r - 8192; node = ts[(rr >> 2) * 6 + 2 + (rr & 3)]; }
    const unsigned* src = (const unsigned*)(seq ? mid : low);
    unsigned u = src[(size_t)node * 64 + p];
    int c0 = 2 * p, c1 = 2 * p + 1;
    float ya = blo(u) * sb[seq * 256 + c0] + sb[seq * 256 + 128 + c0];
    float yb = bhi(u) * sb[seq * 256 + c1] + sb[seq * 256 + 128 + c1];
    ((unsigned*)out)[(size_t)r * 128 + seq * 64 + p] = pk2(ya, yb);
}

// ---------------------------------------------------------------------------
// 2-token attention on bf16 qkv (rows stride 384: q|k|v).
// ---------------------------------------------------------------------------
template<int LAYER>
__global__ __launch_bounds__(256)
void attn_fused(const unsigned short* __restrict__ qkv,
                unsigned short* __restrict__ h, int ntot)
{
    int gw   = (blockIdx.x * 256 + threadIdx.x) >> 6;
    int lane = threadIdx.x & 63;
    if (gw >= ntot) return;
    int qtok, ktok, orow;
    if (LAYER == 1) {
        if      (gw < 4096)  { int g = gw;         qtok = 8192  + g*2; ktok = g*2;          orow = g*2; }
        else if (gw < 8192)  { int g = gw - 4096;  qtok = g*2;         ktok = 8192 + g*2;   orow = 8192 + g*2; }
        else if (gw < 24576) { int g = gw - 8192;  qtok = 16384 + g*2; ktok = (g>>2)*2;     orow = 16384 + g*2; }
        else                 { int g = gw - 24576; qtok = (g>>2)*2;    ktok = 16384 + g*2;  orow = 49152 + g*2; }
    } else {
        qtok = gw * 2; ktok = gw * 2; orow = gw * 2;
    }
    int d = lane * 2;
    unsigned q0 = *(const unsigned*)(qkv + (size_t)qtok * 384 + d);
    unsigned q1 = *(const unsigned*)(qkv + (size_t)(qtok+1) * 384 + d);
    unsigned k0 = *(const unsigned*)(qkv + (size_t)ktok * 384 + 128 + d);
    unsigned k1 = *(const unsigned*)(qkv + (size_t)(ktok+1) * 384 + 128 + d);
    float s00 = blo(q0)*blo(k0) + bhi(q0)*bhi(k0);
    float s01 = blo(q0)*blo(k1) + bhi(q0)*bhi(k1);
    float s10 = blo(q1)*blo(k0) + bhi(q1)*bhi(k0);
    float s11 = blo(q1)*blo(k1) + bhi(q1)*bhi(k1);
#pragma unroll
    for (int off = 32; off; off >>= 1) {
        s00 += __shfl_xor(s00, off);
        s01 += __shfl_xor(s01, off);
        s10 += __shfl_xor(s10, off);
        s11 += __shfl_xor(s11, off);
    }
    const float scale = 0.08838834764831845f;   // 1/sqrt(128)
    s00 *= scale; s01 *= scale; s10 *= scale; s11 *= scale;
    // softmax over QUERY axis (per key column)
    float m0 = fmaxf(s00, s10), m1 = fmaxf(s01, s11);
    float e00 = __expf(s00 - m0), e10 = __expf(s10 - m0);
    float e01 = __expf(s01 - m1), e11 = __expf(s11 - m1);
    float i0 = 1.f / (e00 + e10), i1 = 1.f / (e01 + e11);
    float a00 = e00 * i0, a10 = e10 * i0;
    float a01 = e01 * i1, a11 = e11 * i1;
    unsigned v0 = *(const unsigned*)(qkv + (size_t)ktok * 384 + 256 + d);
    unsigned v1 = *(const unsigned*)(qkv + (size_t)(ktok+1) * 384 + 256 + d);
    float h0x = a00*blo(v0) + a01*blo(v1), h0y = a00*bhi(v0) + a01*bhi(v1);
    float h1x = a10*blo(v0) + a11*blo(v1), h1y = a10*bhi(v0) + a11*bhi(v1);
    *(unsigned*)(h + (size_t)orow * 128 + d)       = pk2(h0x, h0y);
    *(unsigned*)(h + (size_t)(orow + 1) * 128 + d) = pk2(h1x, h1y);
}

// ---------------------------------------------------------------------------
__global__ __launch_bounds__(256)
void scores_kernel(const float* __restrict__ cat, float* __restrict__ scores)
{
    int gw   = (blockIdx.x * 256 + threadIdx.x) >> 6;
    int lane = threadIdx.x & 63;
    if (gw >= 20480) return;
    const float *pa, *pb;
    if (gw < BQ) { pa = cat + (size_t)gw * 128;            pb = cat + (size_t)(BQ + gw) * 128; }
    else { int n = gw - BQ; pa = cat + (size_t)(2*BQ + n) * 128; pb = cat + (size_t)(2*BQ + BQ*NNEG + n) * 128; }
    f32x2 a = *(const f32x2*)(pa + lane * 2);
    f32x2 b = *(const f32x2*)(pb + lane * 2);
    float s = a.x * b.x + a.y * b.y;
#pragma unroll
    for (int off = 32; off; off >>= 1) s += __shfl_xor(s, off);
    if (lane == 0) scores[gw] = s;
}

__global__ __launch_bounds__(256)
void loss_kernel(const float* __restrict__ scores, float* __restrict__ out)
{
    int t = threadIdx.x;
    float acc = 0.f;
    for (int i = t; i < BQ * NNEG; i += 256) {
        int b = i >> 2;
        float x = scores[b] - scores[BQ + i];
        float sig = 1.f / (1.f + __expf(-x));
        acc += __logf(sig + 1e-9f);
    }
    __shared__ float red[256];
    red[t] = acc; __syncthreads();
    for (int s = 128; s > 0; s >>= 1) { if (t < s) red[t] += red[t + s]; __syncthreads(); }
    if (t == 0) out[0] = -red[0] / (float)(BQ * NNEG);
}

// ---------------------------------------------------------------------------
// Weight packing
// ---------------------------------------------------------------------------
__global__ void pack_wc(const float* __restrict__ W2, const float* __restrict__ W3,
                        const float* __restrict__ We, short* __restrict__ WcT)
{
    int k = blockIdx.x, n = threadIdx.x;
    const float* Wrow = (k < 768) ? (W2 + (size_t)k * 128) : (W3 + (size_t)(k - 768) * 128);
    const float* Web  = We + ((k < 768) ? 0 : 128 * 128);
    float acc = 0.f;
    for (int j = 0; j < 128; ++j) acc += Wrow[j] * Web[j * 128 + n];
    WcT[(size_t)n * 1536 + k] = f2b(acc);
}

__global__ __launch_bounds__(128)
void pack_misc(const float* PT, const float* We,
               const float* b2, const float* b3, const float* bemb,
               const float* Wq1, const float* Wk1, const float* Wv1,
               const float* bq1, const float* bk1, const float* bv1,
               const float* Wq2, const float* Wk2, const float* Wv2,
               const float* bq2, const float* bk2, const float* bv2,
               const float* Wlow, const float* Wmid, const float* Wct,
               float* ptab2, float* bias_c,
               short* Wqkv1T, float* bqkv1,
               short* Wqkv2T, float* bqkv2,
               short* WlowT2, short* WmidT2, short* WcatT)
{
    int b = blockIdx.x, t = threadIdx.x;
    if (b < 100) {
        const float* Web = We + 256 * 128;
        float acc = 0.f;
        for (int j = 0; j < 128; ++j) acc += PT[b * 128 + j] * Web[j * 128 + t];
        ptab2[b * 128 + t] = acc;
    } else if (b == 100) {
        float acc = bemb[t];
        for (int j = 0; j < 128; ++j)
            acc += b2[j] * We[j * 128 + t] + b3[j] * We[(128 + j) * 128 + t];
        bias_c[t] = acc;
    } else if (b < 229) {
        int k = b - 101;
        Wqkv1T[(size_t)(      t) * 128 + k] = f2b(Wq1[k * 128 + t]);
        Wqkv1T[(size_t)(128 + t) * 128 + k] = f2b(Wk1[k * 128 + t]);
        Wqkv1T[(size_t)(256 + t) * 128 + k] = f2b(Wv1[k * 128 + t]);
        if (k == 0) { bqkv1[t] = bq1[t]; bqkv1[128 + t] = bk1[t]; bqkv1[256 + t] = bv1[t]; }
    } else if (b < 357) {
        int k = b - 229;
        Wqkv2T[(size_t)(      t) * 128 + k] = f2b(Wq2[k * 128 + t]);
        Wqkv2T[(size_t)(128 + t) * 128 + k] = f2b(Wk2[k * 128 + t]);
        Wqkv2T[(size_t)(256 + t) * 128 + k] = f2b(Wv2[k * 128 + t]);
        if (k == 0) { bqkv2[t] = bq2[t]; bqkv2[128 + t] = bk2[t]; bqkv2[256 + t] = bv2[t]; }
    } else if (b < 485) {
        int k = b - 357;                         // K-concat, 0.5 folded
        short v = f2b(0.5f * Wlow[k * 128 + t]);
        WlowT2[(size_t)t * 256 + k]       = v;
        WlowT2[(size_t)t * 256 + 128 + k] = v;
    } else if (b < 613) {
        int k = b - 485;
        WmidT2[(size_t)t * 256 + k]       = f2b( 0.5f * Wmid[k * 128 + t]);
        WmidT2[(size_t)t * 256 + 128 + k] = f2b(-0.5f * Wmid[k * 128 + t]);
    } else {
        int k = b - 613;   // 0..255
        WcatT[(size_t)t * 256 + k] = f2b(Wct[k * 128 + t]);
    }
}

// ---------------------------------------------------------------------------
extern "C" void kernel_launch(void* const* d_in, const int* in_sizes, int n_in,
                              void* d_out, int out_size, void* d_ws, size_t ws_size,
                              hipStream_t stream)
{
    const float* features = (const float*)d_in[0];
    const int*   price    = (const int*)  d_in[1];
    const int*   adj_row  = (const int*)  d_in[2];
    const int*   adj_col  = (const int*)  d_in[3];
    const float* adj_val  = (const float*)d_in[4];
    const int*   train_set= (const int*)  d_in[5];
    const float* W_cid2   = (const float*)d_in[6];
    const float* b_cid2   = (const float*)d_in[7];
    const float* W_cid3   = (const float*)d_in[8];
    const float* b_cid3   = (const float*)d_in[9];
    const float* ptable   = (const float*)d_in[10];
    const float* W_emb    = (const float*)d_in[11];
    const float* b_emb    = (const float*)d_in[12];
    const float* W_low    = (const float*)d_in[13];
    const float* W_mid    = (const float*)d_in[14];
    const float* bn1_g    = (const float*)d_in[15];
    const float* bn1_b    = (const float*)d_in[16];
    const float* bn2_g    = (const float*)d_in[17];
    const float* bn2_b    = (const float*)d_in[18];
    const float* Wq1 = (const float*)d_in[19]; const float* bq1 = (const float*)d_in[20];
    const float* Wk1 = (const float*)d_in[21]; const float* bk1 = (const float*)d_in[22];
    const float* Wv1 = (const float*)d_in[23]; const float* bv1 = (const float*)d_in[24];
    const float* Wq2 = (const float*)d_in[25]; const float* bq2 = (const float*)d_in[26];
    const float* Wk2 = (const float*)d_in[27]; const float* bk2 = (const float*)d_in[28];
    const float* Wv2 = (const float*)d_in[29]; const float* bv2 = (const float*)d_in[30];
    const float* Wcat= (const float*)d_in[31]; const float* bcat= (const float*)d_in[32];

    float* ws = (float*)d_ws;

    // ---- workspace (float offsets, 16B-aligned) ----
    unsigned short* item_bf = (unsigned short*)(ws);              // 6.4M sh
    unsigned short* ag_bf   = (unsigned short*)(ws + 3200000);
    unsigned short* ag2_bf  = (unsigned short*)(ws + 6400000);
    unsigned short* low_bf  = (unsigned short*)(ws + 9600000);
    unsigned short* mid_bf  = (unsigned short*)(ws + 12800000);
    unsigned short* gath_b  = (unsigned short*)(ws + 16000000);   // 49152*128 sh
    unsigned short* qkv1b   = (unsigned short*)(ws + 19145728);   // 49152*384 sh
    unsigned short* h1b     = (unsigned short*)(ws + 28582912);   // 81920*128 sh
    unsigned short* qkv2b   = (unsigned short*)(ws + 33825792);   // 81920*384 sh
    unsigned short* h2b     = (unsigned short*)(ws + 49554432);   // 81920*128 sh
    float*          cat     = ws + 54797312;                      // 40960*128 f32
    int*            ibase   = (int*)(ws + 60040192);
    int*   rp    = ibase;                    // 50016
    int*   cur   = ibase + 50016;            // 50016
    float* stats = (float*)(ibase + 100032); // 512 (zeroed with cur)
    int*   bsum  = ibase + 100544;           // 64
    int2*  pedge = (int2*)(ibase + 100640);  // 1,600,000 int2
    float* wb    = (float*)(ibase + 3300640);
    short* WcT    = (short*)wb;              // 98304 f
    float* ptab2  = wb + 98304;              // 12800
    float* bias_c = wb + 111104;             // 128
    short* Wqkv1T = (short*)(wb + 111232);   // 24576 f
    float* bqkv1  = wb + 135808;             // 384
    short* Wqkv2T = (short*)(wb + 136192);   // 24576 f
    float* bqkv2  = wb + 160768;             // 384
    short* WlowT2 = (short*)(wb + 161152);   // 16384 f  (128x256 sh)
    short* WmidT2 = (short*)(wb + 177536);   // 16384 f
    short* WcatT  = (short*)(wb + 193920);   // 16384 f
    float* sb     = wb + 210304;             // 512
    float* scores = wb + 210816;             // 20480

    // ---- weight packing ----
    hipLaunchKernelGGL(pack_wc,   dim3(1536), dim3(128), 0, stream, W_cid2, W_cid3, W_emb, WcT);
    hipLaunchKernelGGL(pack_misc, dim3(869),  dim3(128), 0, stream,
                       ptable, W_emb, b_cid2, b_cid3, b_emb,
                       Wq1, Wk1, Wv1, bq1, bk1, bv1,
                       Wq2, Wk2, Wv2, bq2, bk2, bv2,
                       W_low, W_mid, Wcat,
                       ptab2, bias_c, Wqkv1T, bqkv1, Wqkv2T, bqkv2,
                       WlowT2, WmidT2, WcatT);

    // zero cur (50016 ints) + stats (512 floats), contiguous
    hipMemsetAsync(cur, 0, (50016 + 512) * 4, stream);

    // ---- CSR build ----
    hipLaunchKernelGGL(hist_rows,     dim3(6250), dim3(256),  0, stream, adj_row, cur);
    hipLaunchKernelGGL(scan_a,        dim3(49),   dim3(1024), 0, stream, cur, rp, bsum);
    hipLaunchKernelGGL(scan_b,        dim3(1),    dim3(64),   0, stream, bsum, 49);
    hipLaunchKernelGGL(scan_c,        dim3(49),   dim3(1024), 0, stream, rp, cur, bsum);
    hipLaunchKernelGGL(scatter_edges, dim3(6250), dim3(256),  0, stream,
                       adj_row, adj_col, adj_val, cur, pedge);

    // ---- item = relu(features @ Wc + ptab2[price] + bias_c) -> bf16 ----
    hipLaunchKernelGGL(gemm_item, dim3(391), dim3(256), 0, stream,
                       features, WcT, bias_c, price, ptab2, item_bf, NN, 1536);

    // ---- ag = A @ item ; ag2 = A @ ag (bf16 in/out) ----
    hipLaunchKernelGGL(spmm_csr, dim3(12500), dim3(256), 0, stream, rp, pedge, item_bf, ag_bf);
    hipLaunchKernelGGL(spmm_csr, dim3(12500), dim3(256), 0, stream, rp, pedge, ag_bf, ag2_bf);

    // ---- low = [ag|item]@W'low ; mid = [ag2|item]@W'mid (fused, bf16) ----
    hipLaunchKernelGGL(gemm_lowmid, dim3(391, 2), dim3(256), 0, stream,
                       ag_bf, ag2_bf, item_bf, WlowT2, WmidT2, low_bf, mid_bf, NN);

    // ---- BN stats + fold ----
    hipLaunchKernelGGL(colstats, dim3(98, 2), dim3(256), 0, stream, low_bf, mid_bf, stats, NN);
    hipLaunchKernelGGL(bn_scalebias, dim3(1), dim3(256), 0, stream,
                       stats, bn1_g, bn1_b, bn2_g, bn2_b, sb, 1.f / (float)NN);

    // ---- gather + normalize -> bf16 ----
    hipLaunchKernelGGL(gather_norm, dim3(12288), dim3(256), 0, stream,
                       low_bf, mid_bf, sb, train_set, gath_b);

    // ---- layer-1 qkv ----
    hipLaunchKernelGGL((gemm_a16<true>), dim3(384, 3), dim3(256), 0, stream,
                       gath_b, Wqkv1T, bqkv1, nullptr, qkv1b, 384, 49152, 128);

    // ---- layer-1 attention (4 flows fused) ----
    hipLaunchKernelGGL((attn_fused<1>), dim3(10240), dim3(256), 0, stream, qkv1b, h1b, 40960);

    // ---- layer-2 qkv ----
    hipLaunchKernelGGL((gemm_a16<true>), dim3(640, 3), dim3(256), 0, stream,
                       h1b, Wqkv2T, bqkv2, nullptr, qkv2b, 384, 81920, 128);

    // ---- layer-2 attention ----
    hipLaunchKernelGGL((attn_fused<2>), dim3(10240), dim3(256), 0, stream, qkv2b, h2b, 40960);

    // ---- cat GEMM (bf16 in, f32 out) ----
    hipLaunchKernelGGL((gemm_a16<false>), dim3(320, 1), dim3(256), 0, stream,
                       h2b, WcatT, bcat, cat, nullptr, 128, 40960, 256);

    // ---- scores + loss ----
    hipLaunchKernelGGL(scores_kernel, dim3(5120), dim3(256), 0, stream, cat, scores);
    hipLaunchKernelGGL(loss_kernel, dim3(1), dim3(256), 0, stream, scores, (float*)d_out);
}